// Round 5
// baseline (953.087 us; speedup 1.0000x reference)
//
#include <hip/hip_runtime.h>
#include <hip/hip_bf16.h>

#define NNODES 10000
#define NEDGES 320000
#define ETOT   (NEDGES + NNODES)
#define NGRAPH 100
#define CH     250   // HEADS*OUT
#define HOUT   125

// ---------------- CSR build (counting sort by dst) ----------------
__global__ void k_deg(const int* __restrict__ eidx, int* __restrict__ deg){
  int e = blockIdx.x*blockDim.x + threadIdx.x;
  if (e >= ETOT) return;
  int dst = (e < NEDGES) ? eidx[NEDGES + e] : (e - NEDGES);
  atomicAdd(&deg[dst], 1);
}

__global__ void k_scan(const int* __restrict__ deg, int* __restrict__ rowptr){
  __shared__ int sh[1024];
  __shared__ int carry;
  if (threadIdx.x == 0){ carry = 0; rowptr[0] = 0; }
  __syncthreads();
  for (int base = 0; base < NNODES; base += 1024){
    int i = base + threadIdx.x;
    int v = (i < NNODES) ? deg[i] : 0;
    sh[threadIdx.x] = v;
    __syncthreads();
    for (int off = 1; off < 1024; off <<= 1){
      int t = (threadIdx.x >= off) ? sh[threadIdx.x - off] : 0;
      __syncthreads();
      sh[threadIdx.x] += t;
      __syncthreads();
    }
    if (i < NNODES) rowptr[i+1] = carry + sh[threadIdx.x];
    __syncthreads();
    if (threadIdx.x == 1023) carry += sh[1023];
    __syncthreads();
  }
}

// store src node id directly into CSR slot
__global__ void k_fill(const int* __restrict__ eidx, const int* __restrict__ rowptr,
                       int* __restrict__ cursor, int* __restrict__ csr_src){
  int e = blockIdx.x*blockDim.x + threadIdx.x;
  if (e >= ETOT) return;
  int dst, src;
  if (e < NEDGES){ src = eidx[e]; dst = eidx[NEDGES + e]; }
  else           { src = e - NEDGES; dst = src; }
  int pos = atomicAdd(&cursor[dst], 1);
  csr_src[rowptr[dst] + pos] = src;
}

// ---------------- GEMM: C += A[M,K] @ W[K,Ncl]  (fp32, 64x64 tile, 4x4 microtile, split-K) ----------------
// Grid: (ceil(M/64), ceil(N/64), KSPLIT). C must be zeroed before launch (atomic accumulate).
// BM=64 not 128: N=250 gives only 4 col-tiles; grid size is the binding constraint on this
// problem shape (round-4 post-mortem: BM=128 -> 316 blocks -> 11% occupancy -> 89us).
#define BM 64
#define BN 64
#define BK 16
#define KSPLIT 2
__global__ __launch_bounds__(256) void k_gemm(const float* __restrict__ A, const float* __restrict__ W,
                       float* __restrict__ C, int M, int K, int Ncl){
  __shared__ float As[BK][BM+4];   // row stride 68 floats = 272 B (16B-aligned)
  __shared__ float Bs[BK][BN+4];
  int tid = threadIdx.x;
  int bm = blockIdx.x * BM, bn = blockIdx.y * BN;
  // split-K range (BK-multiple chunks)
  int kchunk = ((K + KSPLIT*BK - 1) / (KSPLIT*BK)) * BK;
  int kbeg = blockIdx.z * kchunk;
  int kend = min(K, kbeg + kchunk);
  int tx = tid & 15, ty = tid >> 4;
  int ar = tid >> 2, ak = (tid & 3) * 4;    // A staging: row 0..63, k base 0/4/8/12
  int bk_ = tid >> 4, bn0 = (tid & 15) * 4; // B staging: k-row 0..15, col base 0..60
  float acc[4][4] = {};
  for (int k0 = kbeg; k0 < kend; k0 += BK){
    int grow = bm + ar;
    #pragma unroll
    for (int u = 0; u < 4; ++u){
      int gk = k0 + ak + u;
      float v = 0.f;
      if (grow < M && gk < kend) v = A[(size_t)grow * K + gk];
      As[ak + u][ar] = v;
    }
    int gkb = k0 + bk_;
    #pragma unroll
    for (int u = 0; u < 4; ++u){
      int gn = bn + bn0 + u;
      float v = 0.f;
      if (gkb < kend && gn < Ncl) v = W[(size_t)gkb * Ncl + gn];
      Bs[bk_][bn0 + u] = v;
    }
    __syncthreads();
    #pragma unroll
    for (int k = 0; k < BK; ++k){
      float4 a4 = *(const float4*)&As[k][ty*4];
      float4 b4 = *(const float4*)&Bs[k][tx*4];
      float a[4] = {a4.x, a4.y, a4.z, a4.w};
      float b[4] = {b4.x, b4.y, b4.z, b4.w};
      #pragma unroll
      for (int i = 0; i < 4; ++i)
        #pragma unroll
        for (int j = 0; j < 4; ++j)
          acc[i][j] += a[i] * b[j];
    }
    __syncthreads();
  }
  #pragma unroll
  for (int i = 0; i < 4; ++i){
    int row = bm + ty*4 + i;
    if (row >= M) continue;
    #pragma unroll
    for (int j = 0; j < 4; ++j){
      int col = bn + tx*4 + j;
      if (col < Ncl) atomicAdd(&C[(size_t)row * Ncl + col], acc[i][j]);
    }
  }
}

// ---------------- per-node attention scores e_src, e_dst ----------------
__global__ void k_scores(const float* __restrict__ h, const float* __restrict__ asrc,
                         const float* __restrict__ adst,
                         float* __restrict__ esrc, float* __restrict__ edst){
  int node = (blockIdx.x * blockDim.x + threadIdx.x) >> 6;
  int lane = threadIdx.x & 63;
  if (node >= NNODES) return;
  const float* hr = h + (size_t)node * CH;
  float s0=0,d0=0,s1=0,d1=0;
  for (int j = lane; j < HOUT; j += 64){
    float v0 = hr[j];
    float v1 = hr[HOUT + j];
    s0 += v0 * asrc[j];       d0 += v0 * adst[j];
    s1 += v1 * asrc[HOUT+j];  d1 += v1 * adst[HOUT+j];
  }
  for (int off = 32; off > 0; off >>= 1){
    s0 += __shfl_xor(s0, off);
    d0 += __shfl_xor(d0, off);
    s1 += __shfl_xor(s1, off);
    d1 += __shfl_xor(d1, off);
  }
  if (lane == 0){
    esrc[node*2+0] = s0; esrc[node*2+1] = s1;
    edst[node*2+0] = d0; edst[node*2+1] = d1;
  }
}

// ---------------- per-node softmax -> per-edge alpha (float2 per CSR slot) ----------------
__global__ void k_alpha(const float* __restrict__ esrc, const float* __restrict__ edst,
                        const int* __restrict__ rowptr, const int* __restrict__ csr_src,
                        float2* __restrict__ alpha){
  int node = (blockIdx.x * blockDim.x + threadIdx.x) >> 6;
  int lane = threadIdx.x & 63;
  if (node >= NNODES) return;
  int start = rowptr[node], end = rowptr[node+1];
  float ed0 = edst[node*2+0], ed1 = edst[node*2+1];
  float mx0 = -1e30f, mx1 = -1e30f;
  for (int i = start + lane; i < end; i += 64){
    int src = csr_src[i];
    float e0 = esrc[src*2+0] + ed0; e0 = e0 > 0.f ? e0 : 0.2f*e0;
    float e1 = esrc[src*2+1] + ed1; e1 = e1 > 0.f ? e1 : 0.2f*e1;
    mx0 = fmaxf(mx0, e0); mx1 = fmaxf(mx1, e1);
  }
  for (int off = 32; off > 0; off >>= 1){
    mx0 = fmaxf(mx0, __shfl_xor(mx0, off));
    mx1 = fmaxf(mx1, __shfl_xor(mx1, off));
  }
  float sum0 = 0.f, sum1 = 0.f;
  for (int i = start + lane; i < end; i += 64){
    int src = csr_src[i];
    float e0 = esrc[src*2+0] + ed0; e0 = e0 > 0.f ? e0 : 0.2f*e0;
    float e1 = esrc[src*2+1] + ed1; e1 = e1 > 0.f ? e1 : 0.2f*e1;
    sum0 += expf(e0 - mx0); sum1 += expf(e1 - mx1);
  }
  for (int off = 32; off > 0; off >>= 1){
    sum0 += __shfl_xor(sum0, off);
    sum1 += __shfl_xor(sum1, off);
  }
  float inv0 = 1.f / (sum0 + 1e-16f);
  float inv1 = 1.f / (sum1 + 1e-16f);
  for (int i = start + lane; i < end; i += 64){
    int src = csr_src[i];
    float e0 = esrc[src*2+0] + ed0; e0 = e0 > 0.f ? e0 : 0.2f*e0;
    float e1 = esrc[src*2+1] + ed1; e1 = e1 > 0.f ? e1 : 0.2f*e1;
    alpha[i] = make_float2(expf(e0 - mx0) * inv0, expf(e1 - mx1) * inv1);
  }
}

// ---------------- weighted gather: block(4 waves) per node, LDS cross-wave reduce ----------------
__global__ __launch_bounds__(256) void k_gather(const float* __restrict__ h,
                        const float2* __restrict__ alpha, const int* __restrict__ csr_src,
                        const int* __restrict__ rowptr, const float* __restrict__ bias,
                        float* __restrict__ out){
  int node = blockIdx.x;
  int tid = threadIdx.x, wave = tid >> 6, lane = tid & 63;
  int start = rowptr[node], end = rowptr[node+1];
  bool c1h1 = (lane + 64) >= HOUT;
  bool c3ok = (lane + 192) < CH;
  float acc0=0.f, acc1=0.f, acc2=0.f, acc3=0.f;
  int i = start + wave;
  for (; i + 4 < end; i += 8){
    int s0 = csr_src[i];
    int s1 = csr_src[i + 4];
    float2 a0 = alpha[i];
    float2 a1 = alpha[i + 4];
    const float* h0 = h + (size_t)s0 * CH;
    const float* h1 = h + (size_t)s1 * CH;
    float w0c1 = c1h1 ? a0.y : a0.x;
    float w1c1 = c1h1 ? a1.y : a1.x;
    acc0 += a0.x * h0[lane];
    acc1 += w0c1 * h0[lane + 64];
    acc2 += a0.y * h0[lane + 128];
    if (c3ok) acc3 += a0.y * h0[lane + 192];
    acc0 += a1.x * h1[lane];
    acc1 += w1c1 * h1[lane + 64];
    acc2 += a1.y * h1[lane + 128];
    if (c3ok) acc3 += a1.y * h1[lane + 192];
  }
  if (i < end){
    int s0 = csr_src[i];
    float2 a0 = alpha[i];
    const float* h0 = h + (size_t)s0 * CH;
    float w0c1 = c1h1 ? a0.y : a0.x;
    acc0 += a0.x * h0[lane];
    acc1 += w0c1 * h0[lane + 64];
    acc2 += a0.y * h0[lane + 128];
    if (c3ok) acc3 += a0.y * h0[lane + 192];
  }
  __shared__ float sh[4 * 256];
  float* shw = sh + wave * 256;
  shw[lane]        = acc0;
  shw[lane + 64]   = acc1;
  shw[lane + 128]  = acc2;
  if (c3ok) shw[lane + 192] = acc3;
  __syncthreads();
  if (tid < CH){
    float v = sh[tid] + sh[256 + tid] + sh[512 + tid] + sh[768 + tid] + bias[tid];
    out[(size_t)node * CH + tid] = v > 0.f ? v : 0.f;
  }
}

// ---------------- global mean pool ----------------
__global__ void k_pool(const float* __restrict__ x, const int* __restrict__ batch,
                       float* __restrict__ g, float* __restrict__ cnt){
  int idx = blockIdx.x*blockDim.x + threadIdx.x;
  if (idx >= NNODES * CH) return;
  int n = idx / CH, c = idx % CH;
  int b = batch[n];
  atomicAdd(&g[(size_t)b * CH + c], x[idx]);
  if (c == 0) atomicAdd(&cnt[b], 1.0f);
}

// ---------------- small dense linear: block per row, threads = cols ----------------
__global__ void k_linear(const float* __restrict__ A, const float* __restrict__ W,
                         const float* __restrict__ bias, const float* __restrict__ cnt,
                         float* __restrict__ out, int M, int K, int Ncl, int relu){
  int r = blockIdx.x;
  int c = threadIdx.x;
  if (r >= M || c >= Ncl) return;
  float scale = 1.f;
  if (cnt){ scale = 1.f / fmaxf(cnt[r], 1.f); }
  const float* ar = A + (size_t)r * K;
  float acc = 0.f;
  int k = 0;
  for (; k + 4 <= K; k += 4){
    float a0 = ar[k], a1 = ar[k+1], a2 = ar[k+2], a3 = ar[k+3];
    acc += a0 * W[(size_t)k * Ncl + c];
    acc += a1 * W[(size_t)(k+1) * Ncl + c];
    acc += a2 * W[(size_t)(k+2) * Ncl + c];
    acc += a3 * W[(size_t)(k+3) * Ncl + c];
  }
  for (; k < K; ++k) acc += ar[k] * W[(size_t)k * Ncl + c];
  acc = acc * scale + bias[c];
  if (relu) acc = fmaxf(acc, 0.f);
  out[(size_t)r * Ncl + c] = acc;
}

// ---------------- launch ----------------
extern "C" void kernel_launch(void* const* d_in, const int* in_sizes, int n_in,
                              void* d_out, int out_size, void* d_ws, size_t ws_size,
                              hipStream_t stream){
  const float* x   = (const float*)d_in[0];
  const int* eidx  = (const int*)d_in[1];
  const int* batch = (const int*)d_in[2];

  char* ws = (char*)d_ws;
  size_t off = 0;
  auto alloc = [&](size_t bytes)->void*{
    void* p = ws + off;
    off = (off + bytes + 255) & ~(size_t)255;
    return p;
  };
  float*  xbuf    = (float*) alloc((size_t)NNODES * CH * 4);
  float*  hbuf    = (float*) alloc((size_t)NNODES * CH * 4);
  float*  esrc    = (float*) alloc((size_t)NNODES * 2 * 4);
  float*  edst    = (float*) alloc((size_t)NNODES * 2 * 4);
  int*    deg     = (int*)   alloc((size_t)NNODES * 4);
  int*    rowptr  = (int*)   alloc((size_t)(NNODES + 1) * 4);
  int*    cursor  = (int*)   alloc((size_t)NNODES * 4);
  int*    csr_src = (int*)   alloc((size_t)ETOT * 4);
  float2* alpha   = (float2*)alloc((size_t)ETOT * 8);
  float*  g       = (float*) alloc((size_t)NGRAPH * CH * 4);
  float*  cnt     = (float*) alloc((size_t)NGRAPH * 4);
  float*  m1      = (float*) alloc((size_t)NGRAPH * 200 * 4);
  float*  m2      = (float*) alloc((size_t)NGRAPH * 100 * 4);
  float*  m3      = (float*) alloc((size_t)NGRAPH * 100 * 4);

  hipMemsetAsync(deg,    0, (size_t)NNODES * 4, stream);
  hipMemsetAsync(cursor, 0, (size_t)NNODES * 4, stream);
  hipMemsetAsync(g,      0, (size_t)NGRAPH * CH * 4, stream);
  hipMemsetAsync(cnt,    0, (size_t)NGRAPH * 4, stream);

  k_deg <<<(ETOT + 255)/256, 256, 0, stream>>>(eidx, deg);
  k_scan<<<1, 1024, 0, stream>>>(deg, rowptr);
  k_fill<<<(ETOT + 255)/256, 256, 0, stream>>>(eidx, rowptr, cursor, csr_src);

  int Kdims[4] = {336, CH, CH, CH};
  for (int L = 0; L < 4; ++L){
    const float* W   = (const float*)d_in[3 + 4*L];
    const float* as_ = (const float*)d_in[4 + 4*L];
    const float* ad_ = (const float*)d_in[5 + 4*L];
    const float* bb  = (const float*)d_in[6 + 4*L];
    const float* Ain = (L == 0) ? x : xbuf;
    hipMemsetAsync(hbuf, 0, (size_t)NNODES * CH * 4, stream);   // split-K atomic accumulate
    dim3 gg((NNODES + BM - 1)/BM, (CH + BN - 1)/BN, KSPLIT);
    k_gemm<<<gg, 256, 0, stream>>>(Ain, W, hbuf, NNODES, Kdims[L], CH);
    k_scores<<<(NNODES*64 + 255)/256, 256, 0, stream>>>(hbuf, as_, ad_, esrc, edst);
    k_alpha <<<(NNODES*64 + 255)/256, 256, 0, stream>>>(esrc, edst, rowptr, csr_src, alpha);
    k_gather<<<NNODES, 256, 0, stream>>>(hbuf, alpha, csr_src, rowptr, bb, xbuf);
  }

  k_pool<<<(NNODES*CH + 255)/256, 256, 0, stream>>>(xbuf, batch, g, cnt);

  const float* lw1 = (const float*)d_in[19];
  const float* lb1 = (const float*)d_in[20];
  const float* lw2 = (const float*)d_in[21];
  const float* lb2 = (const float*)d_in[22];
  const float* lw3 = (const float*)d_in[23];
  const float* lb3 = (const float*)d_in[24];
  const float* lw4 = (const float*)d_in[25];
  const float* lb4 = (const float*)d_in[26];

  k_linear<<<NGRAPH, 256, 0, stream>>>(g,  lw1, lb1, cnt,     m1, NGRAPH, 250, 200, 1);
  k_linear<<<NGRAPH, 256, 0, stream>>>(m1, lw2, lb2, nullptr, m2, NGRAPH, 200, 100, 1);
  k_linear<<<NGRAPH, 256, 0, stream>>>(m2, lw3, lb3, nullptr, m3, NGRAPH, 100, 100, 1);
  k_linear<<<NGRAPH, 256, 0, stream>>>(m3, lw4, lb4, nullptr, (float*)d_out, NGRAPH, 100, 29, 0);
}

// Round 6
// 574.037 us; speedup vs baseline: 1.6603x; 1.6603x over previous
//
#include <hip/hip_runtime.h>
#include <hip/hip_bf16.h>

#define NNODES 10000
#define NEDGES 320000
#define ETOT   (NEDGES + NNODES)
#define NGRAPH 100
#define CH     250   // HEADS*OUT
#define HOUT   125
#define MPAD   10048 // 157 * 64
#define KP0    352   // layer-0 K=336 padded to 32-multiple
#define KP1    256   // layers 1-3 K=250 padded

typedef __attribute__((ext_vector_type(8))) short bf16x8;
typedef __attribute__((ext_vector_type(4))) float f32x4;

// ---------------- CSR build (counting sort by dst) ----------------
__global__ void k_deg(const int* __restrict__ eidx, int* __restrict__ deg){
  int e = blockIdx.x*blockDim.x + threadIdx.x;
  if (e >= ETOT) return;
  int dst = (e < NEDGES) ? eidx[NEDGES + e] : (e - NEDGES);
  atomicAdd(&deg[dst], 1);
}

__global__ void k_scan(const int* __restrict__ deg, int* __restrict__ rowptr){
  __shared__ int sh[1024];
  __shared__ int carry;
  if (threadIdx.x == 0){ carry = 0; rowptr[0] = 0; }
  __syncthreads();
  for (int base = 0; base < NNODES; base += 1024){
    int i = base + threadIdx.x;
    int v = (i < NNODES) ? deg[i] : 0;
    sh[threadIdx.x] = v;
    __syncthreads();
    for (int off = 1; off < 1024; off <<= 1){
      int t = (threadIdx.x >= off) ? sh[threadIdx.x - off] : 0;
      __syncthreads();
      sh[threadIdx.x] += t;
      __syncthreads();
    }
    if (i < NNODES) rowptr[i+1] = carry + sh[threadIdx.x];
    __syncthreads();
    if (threadIdx.x == 1023) carry += sh[1023];
    __syncthreads();
  }
}

__global__ void k_fill(const int* __restrict__ eidx, const int* __restrict__ rowptr,
                       int* __restrict__ cursor, int* __restrict__ csr_src){
  int e = blockIdx.x*blockDim.x + threadIdx.x;
  if (e >= ETOT) return;
  int dst, src;
  if (e < NEDGES){ src = eidx[e]; dst = eidx[NEDGES + e]; }
  else           { src = e - NEDGES; dst = src; }
  int pos = atomicAdd(&cursor[dst], 1);
  csr_src[rowptr[dst] + pos] = src;
}

// ---------------- x (fp32) -> bf16 row-major, K padded to KP0 ----------------
__global__ void k_xconv(const float* __restrict__ x, __hip_bfloat16* __restrict__ Ab){
  int idx = blockIdx.x*blockDim.x + threadIdx.x;
  if (idx >= NNODES*336) return;
  int r = idx / 336, k = idx % 336;
  Ab[(size_t)r * KP0 + k] = __float2bfloat16(x[idx]);
  // pad cols [336,352) stay 0xAA poison = finite bf16; multiplied by zeroed W-pad.
}

// ---------------- W [K][250] fp32 -> bf16 B-fragment tiling ----------------
// Layout: Wt[((nt*KC + kc)*16 + n)*32 + kj], nt=col/16, kc=k/32, kj=k%32.
// Lane L of a wave reads n=L&15, kj=(L>>4)*8..+8 -> 16B contiguous, 64 lanes = 4KB coalesced.
// Zero-padded in both k (>=K) and col (>=250).
__global__ void k_wconv(const float* __restrict__ W, __hip_bfloat16* __restrict__ Wt,
                        int K, int Kp){
  int KC = Kp >> 5;
  int total = 16 * Kp * 16;
  int idx = blockIdx.x*blockDim.x + threadIdx.x;
  if (idx >= total) return;
  int nt = idx / (Kp * 16);
  int rem = idx % (Kp * 16);
  int k = rem / 16;
  int n = rem % 16;
  int col = nt * 16 + n;
  float v = (k < K && col < CH) ? W[(size_t)k * CH + col] : 0.f;
  Wt[(((size_t)nt * KC + (k >> 5)) * 16 + n) * 32 + (k & 31)] = __float2bfloat16(v);
}

// ---------------- MFMA GEMM: C[M,250] = A[M,Kp](bf16) @ Wt (bf16 tiled), fp32 out ------------
// No LDS. Block = 4 waves; wave w computes rows [bx*64+w*16, +16) x cols [by*64, +64).
// A-frag: m=lane&15, k=quad*8+j (16B load). B-frag from tiled Wt (coalesced). 
// C/D: col=lane&15, row=quad*4+reg (verified layout).
__global__ __launch_bounds__(256) void k_gemm_mfma(
    const __hip_bfloat16* __restrict__ A, const __hip_bfloat16* __restrict__ Wt,
    float* __restrict__ C, int M, int Kp){
  int wv = threadIdx.x >> 6, lane = threadIdx.x & 63;
  int n16 = lane & 15, q = lane >> 4;
  int KC = Kp >> 5;
  int rowbase = blockIdx.x * 64 + wv * 16;
  int bn = blockIdx.y * 64;
  int nt0 = bn >> 4;
  const __hip_bfloat16* ap = A  + (size_t)(rowbase + n16) * Kp + q * 8;
  const __hip_bfloat16* bp = Wt + ((size_t)nt0 * KC * 16 + n16) * 32 + q * 8;
  f32x4 ac0 = {0.f,0.f,0.f,0.f}, ac1 = ac0, ac2 = ac0, ac3 = ac0;
  for (int kc = 0; kc < KC; ++kc){
    bf16x8 a  = *(const bf16x8*)(ap + (size_t)kc * 32);
    bf16x8 b0 = *(const bf16x8*)(bp + ((size_t)0 * KC + kc) * 512);
    bf16x8 b1 = *(const bf16x8*)(bp + ((size_t)1 * KC + kc) * 512);
    bf16x8 b2 = *(const bf16x8*)(bp + ((size_t)2 * KC + kc) * 512);
    bf16x8 b3 = *(const bf16x8*)(bp + ((size_t)3 * KC + kc) * 512);
    ac0 = __builtin_amdgcn_mfma_f32_16x16x32_bf16(a, b0, ac0, 0, 0, 0);
    ac1 = __builtin_amdgcn_mfma_f32_16x16x32_bf16(a, b1, ac1, 0, 0, 0);
    ac2 = __builtin_amdgcn_mfma_f32_16x16x32_bf16(a, b2, ac2, 0, 0, 0);
    ac3 = __builtin_amdgcn_mfma_f32_16x16x32_bf16(a, b3, ac3, 0, 0, 0);
  }
  #pragma unroll
  for (int r = 0; r < 4; ++r){
    int row = rowbase + q * 4 + r;
    if (row >= M) continue;
    float* cr = C + (size_t)row * CH + bn + n16;
    int col = bn + n16;
    if (col      < CH) cr[0]  = ac0[r];
    if (col + 16 < CH) cr[16] = ac1[r];
    if (col + 32 < CH) cr[32] = ac2[r];
    if (col + 48 < CH) cr[48] = ac3[r];
  }
}

// ---------------- per-node attention scores e_src, e_dst ----------------
__global__ void k_scores(const float* __restrict__ h, const float* __restrict__ asrc,
                         const float* __restrict__ adst,
                         float* __restrict__ esrc, float* __restrict__ edst){
  int node = (blockIdx.x * blockDim.x + threadIdx.x) >> 6;
  int lane = threadIdx.x & 63;
  if (node >= NNODES) return;
  const float* hr = h + (size_t)node * CH;
  float s0=0,d0=0,s1=0,d1=0;
  for (int j = lane; j < HOUT; j += 64){
    float v0 = hr[j];
    float v1 = hr[HOUT + j];
    s0 += v0 * asrc[j];       d0 += v0 * adst[j];
    s1 += v1 * asrc[HOUT+j];  d1 += v1 * adst[HOUT+j];
  }
  for (int off = 32; off > 0; off >>= 1){
    s0 += __shfl_xor(s0, off);
    d0 += __shfl_xor(d0, off);
    s1 += __shfl_xor(s1, off);
    d1 += __shfl_xor(d1, off);
  }
  if (lane == 0){
    esrc[node*2+0] = s0; esrc[node*2+1] = s1;
    edst[node*2+0] = d0; edst[node*2+1] = d1;
  }
}

// ---------------- per-node softmax -> per-edge alpha ----------------
__global__ void k_alpha(const float* __restrict__ esrc, const float* __restrict__ edst,
                        const int* __restrict__ rowptr, const int* __restrict__ csr_src,
                        float2* __restrict__ alpha){
  int node = (blockIdx.x * blockDim.x + threadIdx.x) >> 6;
  int lane = threadIdx.x & 63;
  if (node >= NNODES) return;
  int start = rowptr[node], end = rowptr[node+1];
  float ed0 = edst[node*2+0], ed1 = edst[node*2+1];
  float mx0 = -1e30f, mx1 = -1e30f;
  for (int i = start + lane; i < end; i += 64){
    int src = csr_src[i];
    float e0 = esrc[src*2+0] + ed0; e0 = e0 > 0.f ? e0 : 0.2f*e0;
    float e1 = esrc[src*2+1] + ed1; e1 = e1 > 0.f ? e1 : 0.2f*e1;
    mx0 = fmaxf(mx0, e0); mx1 = fmaxf(mx1, e1);
  }
  for (int off = 32; off > 0; off >>= 1){
    mx0 = fmaxf(mx0, __shfl_xor(mx0, off));
    mx1 = fmaxf(mx1, __shfl_xor(mx1, off));
  }
  float sum0 = 0.f, sum1 = 0.f;
  for (int i = start + lane; i < end; i += 64){
    int src = csr_src[i];
    float e0 = esrc[src*2+0] + ed0; e0 = e0 > 0.f ? e0 : 0.2f*e0;
    float e1 = esrc[src*2+1] + ed1; e1 = e1 > 0.f ? e1 : 0.2f*e1;
    sum0 += expf(e0 - mx0); sum1 += expf(e1 - mx1);
  }
  for (int off = 32; off > 0; off >>= 1){
    sum0 += __shfl_xor(sum0, off);
    sum1 += __shfl_xor(sum1, off);
  }
  float inv0 = 1.f / (sum0 + 1e-16f);
  float inv1 = 1.f / (sum1 + 1e-16f);
  for (int i = start + lane; i < end; i += 64){
    int src = csr_src[i];
    float e0 = esrc[src*2+0] + ed0; e0 = e0 > 0.f ? e0 : 0.2f*e0;
    float e1 = esrc[src*2+1] + ed1; e1 = e1 > 0.f ? e1 : 0.2f*e1;
    alpha[i] = make_float2(expf(e0 - mx0) * inv0, expf(e1 - mx1) * inv1);
  }
}

// ---------------- weighted gather; writes fp32 out + bf16 copy (next layer A) --------------
__global__ __launch_bounds__(256) void k_gather(const float* __restrict__ h,
                        const float2* __restrict__ alpha, const int* __restrict__ csr_src,
                        const int* __restrict__ rowptr, const float* __restrict__ bias,
                        float* __restrict__ out, __hip_bfloat16* __restrict__ outb){
  int node = blockIdx.x;
  int tid = threadIdx.x, wave = tid >> 6, lane = tid & 63;
  int start = rowptr[node], end = rowptr[node+1];
  bool c1h1 = (lane + 64) >= HOUT;
  bool c3ok = (lane + 192) < CH;
  float acc0=0.f, acc1=0.f, acc2=0.f, acc3=0.f;
  int i = start + wave;
  for (; i + 4 < end; i += 8){
    int s0 = csr_src[i];
    int s1 = csr_src[i + 4];
    float2 a0 = alpha[i];
    float2 a1 = alpha[i + 4];
    const float* h0 = h + (size_t)s0 * CH;
    const float* h1 = h + (size_t)s1 * CH;
    float w0c1 = c1h1 ? a0.y : a0.x;
    float w1c1 = c1h1 ? a1.y : a1.x;
    acc0 += a0.x * h0[lane];
    acc1 += w0c1 * h0[lane + 64];
    acc2 += a0.y * h0[lane + 128];
    if (c3ok) acc3 += a0.y * h0[lane + 192];
    acc0 += a1.x * h1[lane];
    acc1 += w1c1 * h1[lane + 64];
    acc2 += a1.y * h1[lane + 128];
    if (c3ok) acc3 += a1.y * h1[lane + 192];
  }
  if (i < end){
    int s0 = csr_src[i];
    float2 a0 = alpha[i];
    const float* h0 = h + (size_t)s0 * CH;
    float w0c1 = c1h1 ? a0.y : a0.x;
    acc0 += a0.x * h0[lane];
    acc1 += w0c1 * h0[lane + 64];
    acc2 += a0.y * h0[lane + 128];
    if (c3ok) acc3 += a0.y * h0[lane + 192];
  }
  __shared__ float sh[4 * 256];
  float* shw = sh + wave * 256;
  shw[lane]        = acc0;
  shw[lane + 64]   = acc1;
  shw[lane + 128]  = acc2;
  if (c3ok) shw[lane + 192] = acc3;
  __syncthreads();
  if (tid < CH){
    float v = sh[tid] + sh[256 + tid] + sh[512 + tid] + sh[768 + tid] + bias[tid];
    v = v > 0.f ? v : 0.f;
    out[(size_t)node * CH + tid] = v;
    outb[(size_t)node * KP1 + tid] = __float2bfloat16(v);
  }
}

// ---------------- global mean pool ----------------
__global__ void k_pool(const float* __restrict__ x, const int* __restrict__ batch,
                       float* __restrict__ g, float* __restrict__ cnt){
  int idx = blockIdx.x*blockDim.x + threadIdx.x;
  if (idx >= NNODES * CH) return;
  int n = idx / CH, c = idx % CH;
  int b = batch[n];
  atomicAdd(&g[(size_t)b * CH + c], x[idx]);
  if (c == 0) atomicAdd(&cnt[b], 1.0f);
}

// ---------------- small dense linear: block per row, threads = cols ----------------
__global__ void k_linear(const float* __restrict__ A, const float* __restrict__ W,
                         const float* __restrict__ bias, const float* __restrict__ cnt,
                         float* __restrict__ out, int M, int K, int Ncl, int relu){
  int r = blockIdx.x;
  int c = threadIdx.x;
  if (r >= M || c >= Ncl) return;
  float scale = 1.f;
  if (cnt){ scale = 1.f / fmaxf(cnt[r], 1.f); }
  const float* ar = A + (size_t)r * K;
  float acc = 0.f;
  int k = 0;
  for (; k + 4 <= K; k += 4){
    float a0 = ar[k], a1 = ar[k+1], a2 = ar[k+2], a3 = ar[k+3];
    acc += a0 * W[(size_t)k * Ncl + c];
    acc += a1 * W[(size_t)(k+1) * Ncl + c];
    acc += a2 * W[(size_t)(k+2) * Ncl + c];
    acc += a3 * W[(size_t)(k+3) * Ncl + c];
  }
  for (; k < K; ++k) acc += ar[k] * W[(size_t)k * Ncl + c];
  acc = acc * scale + bias[c];
  if (relu) acc = fmaxf(acc, 0.f);
  out[(size_t)r * Ncl + c] = acc;
}

// ---------------- launch ----------------
extern "C" void kernel_launch(void* const* d_in, const int* in_sizes, int n_in,
                              void* d_out, int out_size, void* d_ws, size_t ws_size,
                              hipStream_t stream){
  const float* x   = (const float*)d_in[0];
  const int* eidx  = (const int*)d_in[1];
  const int* batch = (const int*)d_in[2];

  char* ws = (char*)d_ws;
  size_t off = 0;
  auto alloc = [&](size_t bytes)->void*{
    void* p = ws + off;
    off = (off + bytes + 255) & ~(size_t)255;
    return p;
  };
  float*  xbuf    = (float*) alloc((size_t)NNODES * CH * 4);
  float*  hbuf    = (float*) alloc((size_t)NNODES * CH * 4);
  __hip_bfloat16* Abf0 = (__hip_bfloat16*)alloc((size_t)MPAD * KP0 * 2); // layer-0 A (bf16)
  __hip_bfloat16* Abf  = (__hip_bfloat16*)alloc((size_t)MPAD * KP1 * 2); // layers 1-3 A (bf16)
  __hip_bfloat16* Wt   = (__hip_bfloat16*)alloc((size_t)16 * KP0 * 16 * 2); // tiled W (max size)
  float*  esrc    = (float*) alloc((size_t)NNODES * 2 * 4);
  float*  edst    = (float*) alloc((size_t)NNODES * 2 * 4);
  int*    deg     = (int*)   alloc((size_t)NNODES * 4);
  int*    rowptr  = (int*)   alloc((size_t)(NNODES + 1) * 4);
  int*    cursor  = (int*)   alloc((size_t)NNODES * 4);
  int*    csr_src = (int*)   alloc((size_t)ETOT * 4);
  float2* alpha   = (float2*)alloc((size_t)ETOT * 8);
  float*  g       = (float*) alloc((size_t)NGRAPH * CH * 4);
  float*  cnt     = (float*) alloc((size_t)NGRAPH * 4);
  float*  m1      = (float*) alloc((size_t)NGRAPH * 200 * 4);
  float*  m2      = (float*) alloc((size_t)NGRAPH * 100 * 4);
  float*  m3      = (float*) alloc((size_t)NGRAPH * 100 * 4);

  hipMemsetAsync(deg,    0, (size_t)NNODES * 4, stream);
  hipMemsetAsync(cursor, 0, (size_t)NNODES * 4, stream);
  hipMemsetAsync(g,      0, (size_t)NGRAPH * CH * 4, stream);
  hipMemsetAsync(cnt,    0, (size_t)NGRAPH * 4, stream);

  k_deg <<<(ETOT + 255)/256, 256, 0, stream>>>(eidx, deg);
  k_scan<<<1, 1024, 0, stream>>>(deg, rowptr);
  k_fill<<<(ETOT + 255)/256, 256, 0, stream>>>(eidx, rowptr, cursor, csr_src);

  k_xconv<<<(NNODES*336 + 255)/256, 256, 0, stream>>>(x, Abf0);

  for (int L = 0; L < 4; ++L){
    const float* W   = (const float*)d_in[3 + 4*L];
    const float* as_ = (const float*)d_in[4 + 4*L];
    const float* ad_ = (const float*)d_in[5 + 4*L];
    const float* bb  = (const float*)d_in[6 + 4*L];
    int K  = (L == 0) ? 336 : CH;
    int Kp = (L == 0) ? KP0 : KP1;
    const __hip_bfloat16* Ain = (L == 0) ? Abf0 : Abf;

    int wtot = 16 * Kp * 16;
    k_wconv<<<(wtot + 255)/256, 256, 0, stream>>>(W, Wt, K, Kp);
    dim3 gg(MPAD/64, 4);
    k_gemm_mfma<<<gg, 256, 0, stream>>>(Ain, Wt, hbuf, NNODES, Kp);
    k_scores<<<(NNODES*64 + 255)/256, 256, 0, stream>>>(hbuf, as_, ad_, esrc, edst);
    k_alpha <<<(NNODES*64 + 255)/256, 256, 0, stream>>>(esrc, edst, rowptr, csr_src, alpha);
    k_gather<<<NNODES, 256, 0, stream>>>(hbuf, alpha, csr_src, rowptr, bb, xbuf, Abf);
  }

  k_pool<<<(NNODES*CH + 255)/256, 256, 0, stream>>>(xbuf, batch, g, cnt);

  const float* lw1 = (const float*)d_in[19];
  const float* lb1 = (const float*)d_in[20];
  const float* lw2 = (const float*)d_in[21];
  const float* lb2 = (const float*)d_in[22];
  const float* lw3 = (const float*)d_in[23];
  const float* lb3 = (const float*)d_in[24];
  const float* lw4 = (const float*)d_in[25];
  const float* lb4 = (const float*)d_in[26];

  k_linear<<<NGRAPH, 256, 0, stream>>>(g,  lw1, lb1, cnt,     m1, NGRAPH, 250, 200, 1);
  k_linear<<<NGRAPH, 256, 0, stream>>>(m1, lw2, lb2, nullptr, m2, NGRAPH, 200, 100, 1);
  k_linear<<<NGRAPH, 256, 0, stream>>>(m2, lw3, lb3, nullptr, m3, NGRAPH, 100, 100, 1);
  k_linear<<<NGRAPH, 256, 0, stream>>>(m3, lw4, lb4, nullptr, (float*)d_out, NGRAPH, 100, 29, 0);
}

// Round 7
// 482.448 us; speedup vs baseline: 1.9755x; 1.1898x over previous
//
#include <hip/hip_runtime.h>
#include <hip/hip_bf16.h>

#define NNODES 10000
#define NEDGES 320000
#define ETOT   (NEDGES + NNODES)
#define NGRAPH 100
#define CH     250   // HEADS*OUT
#define HOUT   125
#define MPAD   10048 // 157 * 64
#define KP0    352   // layer-0 K=336 padded to 32-multiple
#define KP1    256   // layers 1-3 K=250 padded

typedef __attribute__((ext_vector_type(8))) short bf16x8;
typedef __attribute__((ext_vector_type(4))) float f32x4;

// ---------------- CSR build (counting sort by dst) ----------------
__global__ void k_deg(const int* __restrict__ eidx, int* __restrict__ deg){
  int e = blockIdx.x*blockDim.x + threadIdx.x;
  if (e >= ETOT) return;
  int dst = (e < NEDGES) ? eidx[NEDGES + e] : (e - NEDGES);
  atomicAdd(&deg[dst], 1);
}

__global__ void k_scan(const int* __restrict__ deg, int* __restrict__ rowptr){
  __shared__ int sh[1024];
  __shared__ int carry;
  if (threadIdx.x == 0){ carry = 0; rowptr[0] = 0; }
  __syncthreads();
  for (int base = 0; base < NNODES; base += 1024){
    int i = base + threadIdx.x;
    int v = (i < NNODES) ? deg[i] : 0;
    sh[threadIdx.x] = v;
    __syncthreads();
    for (int off = 1; off < 1024; off <<= 1){
      int t = (threadIdx.x >= off) ? sh[threadIdx.x - off] : 0;
      __syncthreads();
      sh[threadIdx.x] += t;
      __syncthreads();
    }
    if (i < NNODES) rowptr[i+1] = carry + sh[threadIdx.x];
    __syncthreads();
    if (threadIdx.x == 1023) carry += sh[1023];
    __syncthreads();
  }
}

__global__ void k_fill(const int* __restrict__ eidx, const int* __restrict__ rowptr,
                       int* __restrict__ cursor, int* __restrict__ csr_src){
  int e = blockIdx.x*blockDim.x + threadIdx.x;
  if (e >= ETOT) return;
  int dst, src;
  if (e < NEDGES){ src = eidx[e]; dst = eidx[NEDGES + e]; }
  else           { src = e - NEDGES; dst = src; }
  int pos = atomicAdd(&cursor[dst], 1);
  csr_src[rowptr[dst] + pos] = src;
}

// ---------------- graph segment boundaries from sorted batch ----------------
__global__ void k_gstart(const int* __restrict__ batch, int* __restrict__ gstart){
  int n = blockIdx.x*blockDim.x + threadIdx.x;
  if (n >= NNODES) return;
  int b1 = batch[n];
  int b0 = (n == 0) ? -1 : batch[n-1];
  for (int b = b0 + 1; b <= b1; ++b) gstart[b] = n;
  if (n == NNODES - 1){
    for (int b = b1 + 1; b <= NGRAPH; ++b) gstart[b] = NNODES;
  }
}

// ---------------- x (fp32) -> bf16 row-major, K padded to KP0 ----------------
__global__ void k_xconv(const float* __restrict__ x, __hip_bfloat16* __restrict__ Ab){
  int idx = blockIdx.x*blockDim.x + threadIdx.x;
  if (idx >= NNODES*336) return;
  int r = idx / 336, k = idx % 336;
  Ab[(size_t)r * KP0 + k] = __float2bfloat16(x[idx]);
  // pad cols [336,352) stay 0xAA poison = finite bf16; multiplied by zeroed W-pad.
}

// ---------------- W [K][250] fp32 -> bf16 B-fragment tiling ----------------
// Layout: Wt[((nt*KC + kc)*16 + n)*32 + kj], nt=col/16, kc=k/32, kj=k%32.
__global__ void k_wconv(const float* __restrict__ W, __hip_bfloat16* __restrict__ Wt,
                        int K, int Kp){
  int KC = Kp >> 5;
  int total = 16 * Kp * 16;
  int idx = blockIdx.x*blockDim.x + threadIdx.x;
  if (idx >= total) return;
  int nt = idx / (Kp * 16);
  int rem = idx % (Kp * 16);
  int k = rem / 16;
  int n = rem % 16;
  int col = nt * 16 + n;
  float v = (k < K && col < CH) ? W[(size_t)k * CH + col] : 0.f;
  Wt[(((size_t)nt * KC + (k >> 5)) * 16 + n) * 32 + (k & 31)] = __float2bfloat16(v);
}

// ---------------- MFMA GEMM: C[M,250] = A[M,Kp](bf16) @ Wt (bf16 tiled), fp32 out ------------
__global__ __launch_bounds__(256) void k_gemm_mfma(
    const __hip_bfloat16* __restrict__ A, const __hip_bfloat16* __restrict__ Wt,
    float* __restrict__ C, int M, int Kp){
  int wv = threadIdx.x >> 6, lane = threadIdx.x & 63;
  int n16 = lane & 15, q = lane >> 4;
  int KC = Kp >> 5;
  int rowbase = blockIdx.x * 64 + wv * 16;
  int bn = blockIdx.y * 64;
  int nt0 = bn >> 4;
  const __hip_bfloat16* ap = A  + (size_t)(rowbase + n16) * Kp + q * 8;
  const __hip_bfloat16* bp = Wt + ((size_t)nt0 * KC * 16 + n16) * 32 + q * 8;
  f32x4 ac0 = {0.f,0.f,0.f,0.f}, ac1 = ac0, ac2 = ac0, ac3 = ac0;
  for (int kc = 0; kc < KC; ++kc){
    bf16x8 a  = *(const bf16x8*)(ap + (size_t)kc * 32);
    bf16x8 b0 = *(const bf16x8*)(bp + ((size_t)0 * KC + kc) * 512);
    bf16x8 b1 = *(const bf16x8*)(bp + ((size_t)1 * KC + kc) * 512);
    bf16x8 b2 = *(const bf16x8*)(bp + ((size_t)2 * KC + kc) * 512);
    bf16x8 b3 = *(const bf16x8*)(bp + ((size_t)3 * KC + kc) * 512);
    ac0 = __builtin_amdgcn_mfma_f32_16x16x32_bf16(a, b0, ac0, 0, 0, 0);
    ac1 = __builtin_amdgcn_mfma_f32_16x16x32_bf16(a, b1, ac1, 0, 0, 0);
    ac2 = __builtin_amdgcn_mfma_f32_16x16x32_bf16(a, b2, ac2, 0, 0, 0);
    ac3 = __builtin_amdgcn_mfma_f32_16x16x32_bf16(a, b3, ac3, 0, 0, 0);
  }
  #pragma unroll
  for (int r = 0; r < 4; ++r){
    int row = rowbase + q * 4 + r;
    if (row >= M) continue;
    float* cr = C + (size_t)row * CH + bn + n16;
    int col = bn + n16;
    if (col      < CH) cr[0]  = ac0[r];
    if (col + 16 < CH) cr[16] = ac1[r];
    if (col + 32 < CH) cr[32] = ac2[r];
    if (col + 48 < CH) cr[48] = ac3[r];
  }
}

// ---------------- per-node attention scores e_src, e_dst ----------------
__global__ void k_scores(const float* __restrict__ h, const float* __restrict__ asrc,
                         const float* __restrict__ adst,
                         float* __restrict__ esrc, float* __restrict__ edst){
  int node = (blockIdx.x * blockDim.x + threadIdx.x) >> 6;
  int lane = threadIdx.x & 63;
  if (node >= NNODES) return;
  const float* hr = h + (size_t)node * CH;
  float s0=0,d0=0,s1=0,d1=0;
  for (int j = lane; j < HOUT; j += 64){
    float v0 = hr[j];
    float v1 = hr[HOUT + j];
    s0 += v0 * asrc[j];       d0 += v0 * adst[j];
    s1 += v1 * asrc[HOUT+j];  d1 += v1 * adst[HOUT+j];
  }
  for (int off = 32; off > 0; off >>= 1){
    s0 += __shfl_xor(s0, off);
    d0 += __shfl_xor(d0, off);
    s1 += __shfl_xor(s1, off);
    d1 += __shfl_xor(d1, off);
  }
  if (lane == 0){
    esrc[node*2+0] = s0; esrc[node*2+1] = s1;
    edst[node*2+0] = d0; edst[node*2+1] = d1;
  }
}

// ---------------- per-node softmax -> per-edge alpha ----------------
__global__ void k_alpha(const float* __restrict__ esrc, const float* __restrict__ edst,
                        const int* __restrict__ rowptr, const int* __restrict__ csr_src,
                        float2* __restrict__ alpha){
  int node = (blockIdx.x * blockDim.x + threadIdx.x) >> 6;
  int lane = threadIdx.x & 63;
  if (node >= NNODES) return;
  int start = rowptr[node], end = rowptr[node+1];
  float ed0 = edst[node*2+0], ed1 = edst[node*2+1];
  float mx0 = -1e30f, mx1 = -1e30f;
  for (int i = start + lane; i < end; i += 64){
    int src = csr_src[i];
    float e0 = esrc[src*2+0] + ed0; e0 = e0 > 0.f ? e0 : 0.2f*e0;
    float e1 = esrc[src*2+1] + ed1; e1 = e1 > 0.f ? e1 : 0.2f*e1;
    mx0 = fmaxf(mx0, e0); mx1 = fmaxf(mx1, e1);
  }
  for (int off = 32; off > 0; off >>= 1){
    mx0 = fmaxf(mx0, __shfl_xor(mx0, off));
    mx1 = fmaxf(mx1, __shfl_xor(mx1, off));
  }
  float sum0 = 0.f, sum1 = 0.f;
  for (int i = start + lane; i < end; i += 64){
    int src = csr_src[i];
    float e0 = esrc[src*2+0] + ed0; e0 = e0 > 0.f ? e0 : 0.2f*e0;
    float e1 = esrc[src*2+1] + ed1; e1 = e1 > 0.f ? e1 : 0.2f*e1;
    sum0 += expf(e0 - mx0); sum1 += expf(e1 - mx1);
  }
  for (int off = 32; off > 0; off >>= 1){
    sum0 += __shfl_xor(sum0, off);
    sum1 += __shfl_xor(sum1, off);
  }
  float inv0 = 1.f / (sum0 + 1e-16f);
  float inv1 = 1.f / (sum1 + 1e-16f);
  for (int i = start + lane; i < end; i += 64){
    int src = csr_src[i];
    float e0 = esrc[src*2+0] + ed0; e0 = e0 > 0.f ? e0 : 0.2f*e0;
    float e1 = esrc[src*2+1] + ed1; e1 = e1 > 0.f ? e1 : 0.2f*e1;
    alpha[i] = make_float2(expf(e0 - mx0) * inv0, expf(e1 - mx1) * inv1);
  }
}

// ---------------- weighted gather; writes fp32 out + bf16 copy (next layer A) --------------
__global__ __launch_bounds__(256) void k_gather(const float* __restrict__ h,
                        const float2* __restrict__ alpha, const int* __restrict__ csr_src,
                        const int* __restrict__ rowptr, const float* __restrict__ bias,
                        float* __restrict__ out, __hip_bfloat16* __restrict__ outb){
  int node = blockIdx.x;
  int tid = threadIdx.x, wave = tid >> 6, lane = tid & 63;
  int start = rowptr[node], end = rowptr[node+1];
  bool c1h1 = (lane + 64) >= HOUT;
  bool c3ok = (lane + 192) < CH;
  float acc0=0.f, acc1=0.f, acc2=0.f, acc3=0.f;
  int i = start + wave;
  for (; i + 4 < end; i += 8){
    int s0 = csr_src[i];
    int s1 = csr_src[i + 4];
    float2 a0 = alpha[i];
    float2 a1 = alpha[i + 4];
    const float* h0 = h + (size_t)s0 * CH;
    const float* h1 = h + (size_t)s1 * CH;
    float w0c1 = c1h1 ? a0.y : a0.x;
    float w1c1 = c1h1 ? a1.y : a1.x;
    acc0 += a0.x * h0[lane];
    acc1 += w0c1 * h0[lane + 64];
    acc2 += a0.y * h0[lane + 128];
    if (c3ok) acc3 += a0.y * h0[lane + 192];
    acc0 += a1.x * h1[lane];
    acc1 += w1c1 * h1[lane + 64];
    acc2 += a1.y * h1[lane + 128];
    if (c3ok) acc3 += a1.y * h1[lane + 192];
  }
  if (i < end){
    int s0 = csr_src[i];
    float2 a0 = alpha[i];
    const float* h0 = h + (size_t)s0 * CH;
    float w0c1 = c1h1 ? a0.y : a0.x;
    acc0 += a0.x * h0[lane];
    acc1 += w0c1 * h0[lane + 64];
    acc2 += a0.y * h0[lane + 128];
    if (c3ok) acc3 += a0.y * h0[lane + 192];
  }
  __shared__ float sh[4 * 256];
  float* shw = sh + wave * 256;
  shw[lane]        = acc0;
  shw[lane + 64]   = acc1;
  shw[lane + 128]  = acc2;
  if (c3ok) shw[lane + 192] = acc3;
  __syncthreads();
  if (tid < CH){
    float v = sh[tid] + sh[256 + tid] + sh[512 + tid] + sh[768 + tid] + bias[tid];
    v = v > 0.f ? v : 0.f;
    out[(size_t)node * CH + tid] = v;
    outb[(size_t)node * KP1 + tid] = __float2bfloat16(v);
  }
}

// ---------------- fused head: segmented mean pool + 4-layer MLP, one block per graph ---------
// batch is sorted, so graph g owns node range [gstart[g], gstart[g+1]).
__global__ __launch_bounds__(256) void k_head(const float* __restrict__ x,
                        const int* __restrict__ gstart,
                        const float* __restrict__ lw1, const float* __restrict__ lb1,
                        const float* __restrict__ lw2, const float* __restrict__ lb2,
                        const float* __restrict__ lw3, const float* __restrict__ lb3,
                        const float* __restrict__ lw4, const float* __restrict__ lb4,
                        float* __restrict__ out){
  int g = blockIdx.x;
  int tid = threadIdx.x;
  int s = gstart[g], e = gstart[g+1];
  __shared__ float gvec[256];
  __shared__ float m1[200];
  __shared__ float m2[112];
  __shared__ float m3[112];
  // phase 1: mean pool (no atomics; coalesced column reads)
  if (tid < CH){
    float a0=0.f,a1=0.f,a2=0.f,a3=0.f;
    int n = s;
    for (; n + 3 < e; n += 4){
      a0 += x[(size_t)n * CH + tid];
      a1 += x[(size_t)(n+1) * CH + tid];
      a2 += x[(size_t)(n+2) * CH + tid];
      a3 += x[(size_t)(n+3) * CH + tid];
    }
    for (; n < e; ++n) a0 += x[(size_t)n * CH + tid];
    float scale = 1.f / fmaxf((float)(e - s), 1.f);
    gvec[tid] = (a0 + a1 + a2 + a3) * scale;
  }
  __syncthreads();
  // phase 2: 250 -> 200, relu
  if (tid < 200){
    float a0=0.f,a1=0.f,a2=0.f,a3=0.f;
    int k = 0;
    for (; k + 3 < CH; k += 4){
      a0 += gvec[k]   * lw1[(size_t)k     * 200 + tid];
      a1 += gvec[k+1] * lw1[(size_t)(k+1) * 200 + tid];
      a2 += gvec[k+2] * lw1[(size_t)(k+2) * 200 + tid];
      a3 += gvec[k+3] * lw1[(size_t)(k+3) * 200 + tid];
    }
    for (; k < CH; ++k) a0 += gvec[k] * lw1[(size_t)k * 200 + tid];
    float v = a0 + a1 + a2 + a3 + lb1[tid];
    m1[tid] = v > 0.f ? v : 0.f;
  }
  __syncthreads();
  // phase 3: 200 -> 100, relu
  if (tid < 100){
    float a0=0.f,a1=0.f,a2=0.f,a3=0.f;
    int k = 0;
    for (; k + 3 < 200; k += 4){
      a0 += m1[k]   * lw2[(size_t)k     * 100 + tid];
      a1 += m1[k+1] * lw2[(size_t)(k+1) * 100 + tid];
      a2 += m1[k+2] * lw2[(size_t)(k+2) * 100 + tid];
      a3 += m1[k+3] * lw2[(size_t)(k+3) * 100 + tid];
    }
    float v = a0 + a1 + a2 + a3 + lb2[tid];
    m2[tid] = v > 0.f ? v : 0.f;
  }
  __syncthreads();
  // phase 4: 100 -> 100, relu
  if (tid < 100){
    float a0=0.f,a1=0.f,a2=0.f,a3=0.f;
    int k = 0;
    for (; k + 3 < 100; k += 4){
      a0 += m2[k]   * lw3[(size_t)k     * 100 + tid];
      a1 += m2[k+1] * lw3[(size_t)(k+1) * 100 + tid];
      a2 += m2[k+2] * lw3[(size_t)(k+2) * 100 + tid];
      a3 += m2[k+3] * lw3[(size_t)(k+3) * 100 + tid];
    }
    float v = a0 + a1 + a2 + a3 + lb3[tid];
    m3[tid] = v > 0.f ? v : 0.f;
  }
  __syncthreads();
  // phase 5: 100 -> 29, no relu
  if (tid < 29){
    float a0=0.f,a1=0.f,a2=0.f,a3=0.f;
    int k = 0;
    for (; k + 3 < 100; k += 4){
      a0 += m3[k]   * lw4[(size_t)k     * 29 + tid];
      a1 += m3[k+1] * lw4[(size_t)(k+1) * 29 + tid];
      a2 += m3[k+2] * lw4[(size_t)(k+2) * 29 + tid];
      a3 += m3[k+3] * lw4[(size_t)(k+3) * 29 + tid];
    }
    out[(size_t)g * 29 + tid] = a0 + a1 + a2 + a3 + lb4[tid];
  }
}

// ---------------- launch ----------------
extern "C" void kernel_launch(void* const* d_in, const int* in_sizes, int n_in,
                              void* d_out, int out_size, void* d_ws, size_t ws_size,
                              hipStream_t stream){
  const float* x   = (const float*)d_in[0];
  const int* eidx  = (const int*)d_in[1];
  const int* batch = (const int*)d_in[2];

  char* ws = (char*)d_ws;
  size_t off = 0;
  auto alloc = [&](size_t bytes)->void*{
    void* p = ws + off;
    off = (off + bytes + 255) & ~(size_t)255;
    return p;
  };
  float*  xbuf    = (float*) alloc((size_t)NNODES * CH * 4);
  float*  hbuf    = (float*) alloc((size_t)NNODES * CH * 4);
  __hip_bfloat16* Abf0 = (__hip_bfloat16*)alloc((size_t)MPAD * KP0 * 2);
  __hip_bfloat16* Abf  = (__hip_bfloat16*)alloc((size_t)MPAD * KP1 * 2);
  __hip_bfloat16* Wt   = (__hip_bfloat16*)alloc((size_t)16 * KP0 * 16 * 2);
  float*  esrc    = (float*) alloc((size_t)NNODES * 2 * 4);
  float*  edst    = (float*) alloc((size_t)NNODES * 2 * 4);
  int*    deg     = (int*)   alloc((size_t)NNODES * 4);
  int*    rowptr  = (int*)   alloc((size_t)(NNODES + 1) * 4);
  int*    cursor  = (int*)   alloc((size_t)NNODES * 4);
  int*    csr_src = (int*)   alloc((size_t)ETOT * 4);
  float2* alpha   = (float2*)alloc((size_t)ETOT * 8);
  int*    gstart  = (int*)   alloc((size_t)(NGRAPH + 1) * 4);

  hipMemsetAsync(deg,    0, (size_t)NNODES * 4, stream);
  hipMemsetAsync(cursor, 0, (size_t)NNODES * 4, stream);

  k_deg   <<<(ETOT + 255)/256, 256, 0, stream>>>(eidx, deg);
  k_scan  <<<1, 1024, 0, stream>>>(deg, rowptr);
  k_fill  <<<(ETOT + 255)/256, 256, 0, stream>>>(eidx, rowptr, cursor, csr_src);
  k_gstart<<<(NNODES + 255)/256, 256, 0, stream>>>(batch, gstart);

  k_xconv<<<(NNODES*336 + 255)/256, 256, 0, stream>>>(x, Abf0);

  for (int L = 0; L < 4; ++L){
    const float* W   = (const float*)d_in[3 + 4*L];
    const float* as_ = (const float*)d_in[4 + 4*L];
    const float* ad_ = (const float*)d_in[5 + 4*L];
    const float* bb  = (const float*)d_in[6 + 4*L];
    int K  = (L == 0) ? 336 : CH;
    int Kp = (L == 0) ? KP0 : KP1;
    const __hip_bfloat16* Ain = (L == 0) ? Abf0 : Abf;

    int wtot = 16 * Kp * 16;
    k_wconv<<<(wtot + 255)/256, 256, 0, stream>>>(W, Wt, K, Kp);
    dim3 gg(MPAD/64, 4);
    k_gemm_mfma<<<gg, 256, 0, stream>>>(Ain, Wt, hbuf, NNODES, Kp);
    k_scores<<<(NNODES*64 + 255)/256, 256, 0, stream>>>(hbuf, as_, ad_, esrc, edst);
    k_alpha <<<(NNODES*64 + 255)/256, 256, 0, stream>>>(esrc, edst, rowptr, csr_src, alpha);
    k_gather<<<NNODES, 256, 0, stream>>>(hbuf, alpha, csr_src, rowptr, bb, xbuf, Abf);
  }

  const float* lw1 = (const float*)d_in[19];
  const float* lb1 = (const float*)d_in[20];
  const float* lw2 = (const float*)d_in[21];
  const float* lb2 = (const float*)d_in[22];
  const float* lw3 = (const float*)d_in[23];
  const float* lb3 = (const float*)d_in[24];
  const float* lw4 = (const float*)d_in[25];
  const float* lb4 = (const float*)d_in[26];

  k_head<<<NGRAPH, 256, 0, stream>>>(xbuf, gstart, lw1, lb1, lw2, lb2, lw3, lb3,
                                     lw4, lb4, (float*)d_out);
}

// Round 8
// 442.338 us; speedup vs baseline: 2.1547x; 1.0907x over previous
//
#include <hip/hip_runtime.h>
#include <hip/hip_bf16.h>

#define NNODES 10000
#define NEDGES 320000
#define ETOT   (NEDGES + NNODES)
#define NGRAPH 100
#define CH     250   // HEADS*OUT
#define HOUT   125
#define MPAD   10048 // 157 * 64
#define KP0    352   // layer-0 K=336 padded to 32-multiple
#define KP1    256   // layers 1-3 K=250 padded

typedef __attribute__((ext_vector_type(8))) short bf16x8;
typedef __attribute__((ext_vector_type(4))) float f32x4;

// ---------------- deg count + graph boundaries (fused) ----------------
__global__ void k_deg(const int* __restrict__ eidx, int* __restrict__ deg,
                      const int* __restrict__ batch, int* __restrict__ gstart){
  int e = blockIdx.x*blockDim.x + threadIdx.x;
  if (e < ETOT){
    int dst = (e < NEDGES) ? eidx[NEDGES + e] : (e - NEDGES);
    atomicAdd(&deg[dst], 1);
  }
  if (e < NNODES){
    int b1 = batch[e];
    int b0 = (e == 0) ? -1 : batch[e-1];
    for (int b = b0 + 1; b <= b1; ++b) gstart[b] = e;
    if (e == NNODES - 1){
      for (int b = b1 + 1; b <= NGRAPH; ++b) gstart[b] = NNODES;
    }
  }
}

// ---------------- exclusive scan of deg -> rowptr (1 block, 1024 thr, 2 barriers) ----------
__global__ __launch_bounds__(1024) void k_scan(const int* __restrict__ deg, int* __restrict__ rowptr){
  const int CHUNK = 10;   // 1024*10 = 10240 >= NNODES
  int tid = threadIdx.x;
  int base = tid * CHUNK;
  int sum = 0;
  #pragma unroll
  for (int u = 0; u < CHUNK; ++u){
    int i = base + u;
    sum += (i < NNODES) ? deg[i] : 0;
  }
  int lane = tid & 63, wv = tid >> 6;
  int v = sum;
  #pragma unroll
  for (int off = 1; off < 64; off <<= 1){
    int t = __shfl_up(v, off);
    if (lane >= off) v += t;
  }
  __shared__ int wtot[16];
  __shared__ int woff[16];
  if (lane == 63) wtot[wv] = v;
  __syncthreads();
  if (tid == 0){
    int acc = 0;
    #pragma unroll
    for (int w = 0; w < 16; ++w){ woff[w] = acc; acc += wtot[w]; }
  }
  __syncthreads();
  int run = woff[wv] + v - sum;   // exclusive prefix of this thread's chunk
  #pragma unroll
  for (int u = 0; u < CHUNK; ++u){
    int i = base + u;
    if (i < NNODES){
      run += deg[i];
      rowptr[i+1] = run;
    }
  }
  if (tid == 0) rowptr[0] = 0;
}

__global__ void k_fill(const int* __restrict__ eidx, const int* __restrict__ rowptr,
                       int* __restrict__ cursor, int* __restrict__ csr_src){
  int e = blockIdx.x*blockDim.x + threadIdx.x;
  if (e >= ETOT) return;
  int dst, src;
  if (e < NEDGES){ src = eidx[e]; dst = eidx[NEDGES + e]; }
  else           { src = e - NEDGES; dst = src; }
  int pos = atomicAdd(&cursor[dst], 1);
  csr_src[rowptr[dst] + pos] = src;
}

// ---------------- x (fp32) -> bf16 row-major, K padded to KP0 ----------------
__global__ void k_xconv(const float* __restrict__ x, __hip_bfloat16* __restrict__ Ab){
  int idx = blockIdx.x*blockDim.x + threadIdx.x;
  if (idx >= NNODES*336) return;
  int r = idx / 336, k = idx % 336;
  Ab[(size_t)r * KP0 + k] = __float2bfloat16(x[idx]);
}

// ---------------- all 4 W -> bf16 B-fragment tiling, one launch ----------------
// Wt layout: [((nt*KC + kc)*16 + n)*32 + kj], nt=col/16, kc=k/32, kj=k%32; zero-padded.
__global__ void k_wconv_all(const float* __restrict__ W0, const float* __restrict__ W1,
                            const float* __restrict__ W2, const float* __restrict__ W3,
                            __hip_bfloat16* __restrict__ Wt0, __hip_bfloat16* __restrict__ Wt1,
                            __hip_bfloat16* __restrict__ Wt2, __hip_bfloat16* __restrict__ Wt3){
  const int T0 = 16 * KP0 * 16;   // 90112
  const int T1 = 16 * KP1 * 16;   // 65536
  int idx = blockIdx.x*blockDim.x + threadIdx.x;
  const float* W; __hip_bfloat16* Wt; int K, Kp, li;
  if (idx < T0)              { W = W0; Wt = Wt0; K = 336; Kp = KP0; li = idx; }
  else if (idx < T0 +   T1)  { W = W1; Wt = Wt1; K = CH;  Kp = KP1; li = idx - T0; }
  else if (idx < T0 + 2*T1)  { W = W2; Wt = Wt2; K = CH;  Kp = KP1; li = idx - T0 - T1; }
  else if (idx < T0 + 3*T1)  { W = W3; Wt = Wt3; K = CH;  Kp = KP1; li = idx - T0 - 2*T1; }
  else return;
  int KC = Kp >> 5;
  int nt = li / (Kp * 16);
  int rem = li % (Kp * 16);
  int k = rem / 16;
  int n = rem % 16;
  int col = nt * 16 + n;
  float v = (k < K && col < CH) ? W[(size_t)k * CH + col] : 0.f;
  Wt[(((size_t)nt * KC + (k >> 5)) * 16 + n) * 32 + (k & 31)] = __float2bfloat16(v);
}

// ---------------- MFMA GEMM: h fp32 (scores) + bf16 copy (gather) ----------------
__global__ __launch_bounds__(256) void k_gemm_mfma(
    const __hip_bfloat16* __restrict__ A, const __hip_bfloat16* __restrict__ Wt,
    float* __restrict__ C, __hip_bfloat16* __restrict__ Cb, int M, int Kp){
  int wv = threadIdx.x >> 6, lane = threadIdx.x & 63;
  int n16 = lane & 15, q = lane >> 4;
  int KC = Kp >> 5;
  int rowbase = blockIdx.x * 64 + wv * 16;
  int bn = blockIdx.y * 64;
  int nt0 = bn >> 4;
  const __hip_bfloat16* ap = A  + (size_t)(rowbase + n16) * Kp + q * 8;
  const __hip_bfloat16* bp = Wt + ((size_t)nt0 * KC * 16 + n16) * 32 + q * 8;
  f32x4 ac0 = {0.f,0.f,0.f,0.f}, ac1 = ac0, ac2 = ac0, ac3 = ac0;
  for (int kc = 0; kc < KC; ++kc){
    bf16x8 a  = *(const bf16x8*)(ap + (size_t)kc * 32);
    bf16x8 b0 = *(const bf16x8*)(bp + ((size_t)0 * KC + kc) * 512);
    bf16x8 b1 = *(const bf16x8*)(bp + ((size_t)1 * KC + kc) * 512);
    bf16x8 b2 = *(const bf16x8*)(bp + ((size_t)2 * KC + kc) * 512);
    bf16x8 b3 = *(const bf16x8*)(bp + ((size_t)3 * KC + kc) * 512);
    ac0 = __builtin_amdgcn_mfma_f32_16x16x32_bf16(a, b0, ac0, 0, 0, 0);
    ac1 = __builtin_amdgcn_mfma_f32_16x16x32_bf16(a, b1, ac1, 0, 0, 0);
    ac2 = __builtin_amdgcn_mfma_f32_16x16x32_bf16(a, b2, ac2, 0, 0, 0);
    ac3 = __builtin_amdgcn_mfma_f32_16x16x32_bf16(a, b3, ac3, 0, 0, 0);
  }
  #pragma unroll
  for (int r = 0; r < 4; ++r){
    int row = rowbase + q * 4 + r;
    if (row >= M) continue;
    int col = bn + n16;
    float* cr = C + (size_t)row * CH + col;
    __hip_bfloat16* cb = Cb + (size_t)row * CH + col;
    if (col      < CH){ cr[0]  = ac0[r]; cb[0]  = __float2bfloat16(ac0[r]); }
    if (col + 16 < CH){ cr[16] = ac1[r]; cb[16] = __float2bfloat16(ac1[r]); }
    if (col + 32 < CH){ cr[32] = ac2[r]; cb[32] = __float2bfloat16(ac2[r]); }
    if (col + 48 < CH){ cr[48] = ac3[r]; cb[48] = __float2bfloat16(ac3[r]); }
  }
}

// ---------------- per-node attention scores (fp32 h, accuracy-critical) ----------------
__global__ void k_scores(const float* __restrict__ h, const float* __restrict__ asrc,
                         const float* __restrict__ adst,
                         float* __restrict__ esrc, float* __restrict__ edst){
  int node = (blockIdx.x * blockDim.x + threadIdx.x) >> 6;
  int lane = threadIdx.x & 63;
  if (node >= NNODES) return;
  const float* hr = h + (size_t)node * CH;
  float s0=0,d0=0,s1=0,d1=0;
  for (int j = lane; j < HOUT; j += 64){
    float v0 = hr[j];
    float v1 = hr[HOUT + j];
    s0 += v0 * asrc[j];       d0 += v0 * adst[j];
    s1 += v1 * asrc[HOUT+j];  d1 += v1 * adst[HOUT+j];
  }
  for (int off = 32; off > 0; off >>= 1){
    s0 += __shfl_xor(s0, off);
    d0 += __shfl_xor(d0, off);
    s1 += __shfl_xor(s1, off);
    d1 += __shfl_xor(d1, off);
  }
  if (lane == 0){
    esrc[node*2+0] = s0; esrc[node*2+1] = s1;
    edst[node*2+0] = d0; edst[node*2+1] = d1;
  }
}

// ---------------- per-node softmax -> per-edge alpha ----------------
__global__ void k_alpha(const float* __restrict__ esrc, const float* __restrict__ edst,
                        const int* __restrict__ rowptr, const int* __restrict__ csr_src,
                        float2* __restrict__ alpha){
  int node = (blockIdx.x * blockDim.x + threadIdx.x) >> 6;
  int lane = threadIdx.x & 63;
  if (node >= NNODES) return;
  int start = rowptr[node], end = rowptr[node+1];
  float ed0 = edst[node*2+0], ed1 = edst[node*2+1];
  float mx0 = -1e30f, mx1 = -1e30f;
  for (int i = start + lane; i < end; i += 64){
    int src = csr_src[i];
    float e0 = esrc[src*2+0] + ed0; e0 = e0 > 0.f ? e0 : 0.2f*e0;
    float e1 = esrc[src*2+1] + ed1; e1 = e1 > 0.f ? e1 : 0.2f*e1;
    mx0 = fmaxf(mx0, e0); mx1 = fmaxf(mx1, e1);
  }
  for (int off = 32; off > 0; off >>= 1){
    mx0 = fmaxf(mx0, __shfl_xor(mx0, off));
    mx1 = fmaxf(mx1, __shfl_xor(mx1, off));
  }
  float sum0 = 0.f, sum1 = 0.f;
  for (int i = start + lane; i < end; i += 64){
    int src = csr_src[i];
    float e0 = esrc[src*2+0] + ed0; e0 = e0 > 0.f ? e0 : 0.2f*e0;
    float e1 = esrc[src*2+1] + ed1; e1 = e1 > 0.f ? e1 : 0.2f*e1;
    sum0 += expf(e0 - mx0); sum1 += expf(e1 - mx1);
  }
  for (int off = 32; off > 0; off >>= 1){
    sum0 += __shfl_xor(sum0, off);
    sum1 += __shfl_xor(sum1, off);
  }
  float inv0 = 1.f / (sum0 + 1e-16f);
  float inv1 = 1.f / (sum1 + 1e-16f);
  for (int i = start + lane; i < end; i += 64){
    int src = csr_src[i];
    float e0 = esrc[src*2+0] + ed0; e0 = e0 > 0.f ? e0 : 0.2f*e0;
    float e1 = esrc[src*2+1] + ed1; e1 = e1 > 0.f ? e1 : 0.2f*e1;
    alpha[i] = make_float2(expf(e0 - mx0) * inv0, expf(e1 - mx1) * inv1);
  }
}

// ---------------- weighted gather over bf16 h; fp32 out + bf16 copy (next A) --------------
__global__ __launch_bounds__(256) void k_gather(const __hip_bfloat16* __restrict__ h,
                        const float2* __restrict__ alpha, const int* __restrict__ csr_src,
                        const int* __restrict__ rowptr, const float* __restrict__ bias,
                        float* __restrict__ out, __hip_bfloat16* __restrict__ outb){
  int node = blockIdx.x;
  int tid = threadIdx.x, wave = tid >> 6, lane = tid & 63;
  int start = rowptr[node], end = rowptr[node+1];
  bool c1h1 = (lane + 64) >= HOUT;
  bool c3ok = (lane + 192) < CH;
  float acc0=0.f, acc1=0.f, acc2=0.f, acc3=0.f;
  int i = start + wave;
  for (; i + 4 < end; i += 8){
    int s0 = csr_src[i];
    int s1 = csr_src[i + 4];
    float2 a0 = alpha[i];
    float2 a1 = alpha[i + 4];
    const __hip_bfloat16* h0 = h + (size_t)s0 * CH;
    const __hip_bfloat16* h1 = h + (size_t)s1 * CH;
    float w0c1 = c1h1 ? a0.y : a0.x;
    float w1c1 = c1h1 ? a1.y : a1.x;
    acc0 += a0.x * __bfloat162float(h0[lane]);
    acc1 += w0c1 * __bfloat162float(h0[lane + 64]);
    acc2 += a0.y * __bfloat162float(h0[lane + 128]);
    if (c3ok) acc3 += a0.y * __bfloat162float(h0[lane + 192]);
    acc0 += a1.x * __bfloat162float(h1[lane]);
    acc1 += w1c1 * __bfloat162float(h1[lane + 64]);
    acc2 += a1.y * __bfloat162float(h1[lane + 128]);
    if (c3ok) acc3 += a1.y * __bfloat162float(h1[lane + 192]);
  }
  if (i < end){
    int s0 = csr_src[i];
    float2 a0 = alpha[i];
    const __hip_bfloat16* h0 = h + (size_t)s0 * CH;
    float w0c1 = c1h1 ? a0.y : a0.x;
    acc0 += a0.x * __bfloat162float(h0[lane]);
    acc1 += w0c1 * __bfloat162float(h0[lane + 64]);
    acc2 += a0.y * __bfloat162float(h0[lane + 128]);
    if (c3ok) acc3 += a0.y * __bfloat162float(h0[lane + 192]);
  }
  __shared__ float sh[4 * 256];
  float* shw = sh + wave * 256;
  shw[lane]        = acc0;
  shw[lane + 64]   = acc1;
  shw[lane + 128]  = acc2;
  if (c3ok) shw[lane + 192] = acc3;
  __syncthreads();
  if (tid < CH){
    float v = sh[tid] + sh[256 + tid] + sh[512 + tid] + sh[768 + tid] + bias[tid];
    v = v > 0.f ? v : 0.f;
    out[(size_t)node * CH + tid] = v;
    outb[(size_t)node * KP1 + tid] = __float2bfloat16(v);
  }
}

// ---------------- fused head: segmented mean pool + 4-layer MLP, one block per graph ---------
__global__ __launch_bounds__(256) void k_head(const float* __restrict__ x,
                        const int* __restrict__ gstart,
                        const float* __restrict__ lw1, const float* __restrict__ lb1,
                        const float* __restrict__ lw2, const float* __restrict__ lb2,
                        const float* __restrict__ lw3, const float* __restrict__ lb3,
                        const float* __restrict__ lw4, const float* __restrict__ lb4,
                        float* __restrict__ out){
  int g = blockIdx.x;
  int tid = threadIdx.x;
  int s = gstart[g], e = gstart[g+1];
  __shared__ float gvec[256];
  __shared__ float m1[200];
  __shared__ float m2[112];
  __shared__ float m3[112];
  if (tid < CH){
    float a0=0.f,a1=0.f,a2=0.f,a3=0.f;
    int n = s;
    for (; n + 3 < e; n += 4){
      a0 += x[(size_t)n * CH + tid];
      a1 += x[(size_t)(n+1) * CH + tid];
      a2 += x[(size_t)(n+2) * CH + tid];
      a3 += x[(size_t)(n+3) * CH + tid];
    }
    for (; n < e; ++n) a0 += x[(size_t)n * CH + tid];
    float scale = 1.f / fmaxf((float)(e - s), 1.f);
    gvec[tid] = (a0 + a1 + a2 + a3) * scale;
  }
  __syncthreads();
  if (tid < 200){
    float a0=0.f,a1=0.f,a2=0.f,a3=0.f;
    int k = 0;
    for (; k + 3 < CH; k += 4){
      a0 += gvec[k]   * lw1[(size_t)k     * 200 + tid];
      a1 += gvec[k+1] * lw1[(size_t)(k+1) * 200 + tid];
      a2 += gvec[k+2] * lw1[(size_t)(k+2) * 200 + tid];
      a3 += gvec[k+3] * lw1[(size_t)(k+3) * 200 + tid];
    }
    for (; k < CH; ++k) a0 += gvec[k] * lw1[(size_t)k * 200 + tid];
    float v = a0 + a1 + a2 + a3 + lb1[tid];
    m1[tid] = v > 0.f ? v : 0.f;
  }
  __syncthreads();
  if (tid < 100){
    float a0=0.f,a1=0.f,a2=0.f,a3=0.f;
    for (int k = 0; k + 3 < 200; k += 4){
      a0 += m1[k]   * lw2[(size_t)k     * 100 + tid];
      a1 += m1[k+1] * lw2[(size_t)(k+1) * 100 + tid];
      a2 += m1[k+2] * lw2[(size_t)(k+2) * 100 + tid];
      a3 += m1[k+3] * lw2[(size_t)(k+3) * 100 + tid];
    }
    float v = a0 + a1 + a2 + a3 + lb2[tid];
    m2[tid] = v > 0.f ? v : 0.f;
  }
  __syncthreads();
  if (tid < 100){
    float a0=0.f,a1=0.f,a2=0.f,a3=0.f;
    for (int k = 0; k + 3 < 100; k += 4){
      a0 += m2[k]   * lw3[(size_t)k     * 100 + tid];
      a1 += m2[k+1] * lw3[(size_t)(k+1) * 100 + tid];
      a2 += m2[k+2] * lw3[(size_t)(k+2) * 100 + tid];
      a3 += m2[k+3] * lw3[(size_t)(k+3) * 100 + tid];
    }
    float v = a0 + a1 + a2 + a3 + lb3[tid];
    m3[tid] = v > 0.f ? v : 0.f;
  }
  __syncthreads();
  if (tid < 29){
    float a0=0.f,a1=0.f,a2=0.f,a3=0.f;
    for (int k = 0; k + 3 < 100; k += 4){
      a0 += m3[k]   * lw4[(size_t)k     * 29 + tid];
      a1 += m3[k+1] * lw4[(size_t)(k+1) * 29 + tid];
      a2 += m3[k+2] * lw4[(size_t)(k+2) * 29 + tid];
      a3 += m3[k+3] * lw4[(size_t)(k+3) * 29 + tid];
    }
    out[(size_t)g * 29 + tid] = a0 + a1 + a2 + a3 + lb4[tid];
  }
}

// ---------------- launch ----------------
extern "C" void kernel_launch(void* const* d_in, const int* in_sizes, int n_in,
                              void* d_out, int out_size, void* d_ws, size_t ws_size,
                              hipStream_t stream){
  const float* x   = (const float*)d_in[0];
  const int* eidx  = (const int*)d_in[1];
  const int* batch = (const int*)d_in[2];

  char* ws = (char*)d_ws;
  size_t off = 0;
  auto alloc = [&](size_t bytes)->void*{
    void* p = ws + off;
    off = (off + bytes + 255) & ~(size_t)255;
    return p;
  };
  float*  xbuf    = (float*) alloc((size_t)NNODES * CH * 4);
  float*  hbuf    = (float*) alloc((size_t)NNODES * CH * 4);
  __hip_bfloat16* hb16 = (__hip_bfloat16*)alloc((size_t)NNODES * CH * 2);
  __hip_bfloat16* Abf0 = (__hip_bfloat16*)alloc((size_t)MPAD * KP0 * 2);
  __hip_bfloat16* Abf  = (__hip_bfloat16*)alloc((size_t)MPAD * KP1 * 2);
  __hip_bfloat16* Wt0  = (__hip_bfloat16*)alloc((size_t)16 * KP0 * 16 * 2);
  __hip_bfloat16* Wt1  = (__hip_bfloat16*)alloc((size_t)16 * KP1 * 16 * 2);
  __hip_bfloat16* Wt2  = (__hip_bfloat16*)alloc((size_t)16 * KP1 * 16 * 2);
  __hip_bfloat16* Wt3  = (__hip_bfloat16*)alloc((size_t)16 * KP1 * 16 * 2);
  float*  esrc    = (float*) alloc((size_t)NNODES * 2 * 4);
  float*  edst    = (float*) alloc((size_t)NNODES * 2 * 4);
  int*    deg     = (int*)   alloc((size_t)NNODES * 4);
  int*    rowptr  = (int*)   alloc((size_t)(NNODES + 1) * 4);
  int*    cursor  = (int*)   alloc((size_t)NNODES * 4);
  int*    csr_src = (int*)   alloc((size_t)ETOT * 4);
  float2* alpha   = (float2*)alloc((size_t)ETOT * 8);
  int*    gstart  = (int*)   alloc((size_t)(NGRAPH + 1) * 4);

  hipMemsetAsync(deg,    0, (size_t)NNODES * 4, stream);
  hipMemsetAsync(cursor, 0, (size_t)NNODES * 4, stream);

  k_deg <<<(ETOT + 255)/256, 256, 0, stream>>>(eidx, deg, batch, gstart);
  k_scan<<<1, 1024, 0, stream>>>(deg, rowptr);
  k_fill<<<(ETOT + 255)/256, 256, 0, stream>>>(eidx, rowptr, cursor, csr_src);

  k_xconv<<<(NNODES*336 + 255)/256, 256, 0, stream>>>(x, Abf0);
  {
    int wtot = 16*KP0*16 + 3*16*KP1*16;
    k_wconv_all<<<(wtot + 255)/256, 256, 0, stream>>>(
        (const float*)d_in[3], (const float*)d_in[7], (const float*)d_in[11], (const float*)d_in[15],
        Wt0, Wt1, Wt2, Wt3);
  }

  const __hip_bfloat16* Wts[4] = {Wt0, Wt1, Wt2, Wt3};
  for (int L = 0; L < 4; ++L){
    const float* as_ = (const float*)d_in[4 + 4*L];
    const float* ad_ = (const float*)d_in[5 + 4*L];
    const float* bb  = (const float*)d_in[6 + 4*L];
    int Kp = (L == 0) ? KP0 : KP1;
    const __hip_bfloat16* Ain = (L == 0) ? Abf0 : Abf;

    dim3 gg(MPAD/64, 4);
    k_gemm_mfma<<<gg, 256, 0, stream>>>(Ain, Wts[L], hbuf, hb16, NNODES, Kp);
    k_scores<<<(NNODES*64 + 255)/256, 256, 0, stream>>>(hbuf, as_, ad_, esrc, edst);
    k_alpha <<<(NNODES*64 + 255)/256, 256, 0, stream>>>(esrc, edst, rowptr, csr_src, alpha);
    k_gather<<<NNODES, 256, 0, stream>>>(hb16, alpha, csr_src, rowptr, bb, xbuf, Abf);
  }

  const float* lw1 = (const float*)d_in[19];
  const float* lb1 = (const float*)d_in[20];
  const float* lw2 = (const float*)d_in[21];
  const float* lb2 = (const float*)d_in[22];
  const float* lw3 = (const float*)d_in[23];
  const float* lb3 = (const float*)d_in[24];
  const float* lw4 = (const float*)d_in[25];
  const float* lb4 = (const float*)d_in[26];

  k_head<<<NGRAPH, 256, 0, stream>>>(xbuf, gstart, lw1, lb1, lw2, lb2, lw3, lb3,
                                     lw4, lb4, (float*)d_out);
}

// Round 9
// 408.857 us; speedup vs baseline: 2.3311x; 1.0819x over previous
//
#include <hip/hip_runtime.h>
#include <hip/hip_bf16.h>

#define NNODES 10000
#define NEDGES 320000
#define ETOT   (NEDGES + NNODES)
#define NGRAPH 100
#define CH     250   // HEADS*OUT
#define HOUT   125
#define MPAD   10048 // 157 * 64
#define KP0    352   // layer-0 K=336 padded to 32-multiple
#define KP1    256   // layers 1-3 K=250 padded
#define DCAP   256   // per-node edge cache in LDS (deg ~Poisson(33); >256 handled by fallback)

typedef __attribute__((ext_vector_type(8))) short bf16x8;
typedef __attribute__((ext_vector_type(4))) float f32x4;

// ---------------- deg count + graph boundaries (fused) ----------------
__global__ void k_deg(const int* __restrict__ eidx, int* __restrict__ deg,
                      const int* __restrict__ batch, int* __restrict__ gstart){
  int e = blockIdx.x*blockDim.x + threadIdx.x;
  if (e < ETOT){
    int dst = (e < NEDGES) ? eidx[NEDGES + e] : (e - NEDGES);
    atomicAdd(&deg[dst], 1);
  }
  if (e < NNODES){
    int b1 = batch[e];
    int b0 = (e == 0) ? -1 : batch[e-1];
    for (int b = b0 + 1; b <= b1; ++b) gstart[b] = e;
    if (e == NNODES - 1){
      for (int b = b1 + 1; b <= NGRAPH; ++b) gstart[b] = NNODES;
    }
  }
}

// ---------------- exclusive scan of deg -> rowptr (1 block, 1024 thr) ----------
__global__ __launch_bounds__(1024) void k_scan(const int* __restrict__ deg, int* __restrict__ rowptr){
  const int CHUNK = 10;
  int tid = threadIdx.x;
  int base = tid * CHUNK;
  int sum = 0;
  #pragma unroll
  for (int u = 0; u < CHUNK; ++u){
    int i = base + u;
    sum += (i < NNODES) ? deg[i] : 0;
  }
  int lane = tid & 63, wv = tid >> 6;
  int v = sum;
  #pragma unroll
  for (int off = 1; off < 64; off <<= 1){
    int t = __shfl_up(v, off);
    if (lane >= off) v += t;
  }
  __shared__ int wtot[16];
  __shared__ int woff[16];
  if (lane == 63) wtot[wv] = v;
  __syncthreads();
  if (tid == 0){
    int acc = 0;
    #pragma unroll
    for (int w = 0; w < 16; ++w){ woff[w] = acc; acc += wtot[w]; }
  }
  __syncthreads();
  int run = woff[wv] + v - sum;
  #pragma unroll
  for (int u = 0; u < CHUNK; ++u){
    int i = base + u;
    if (i < NNODES){
      run += deg[i];
      rowptr[i+1] = run;
    }
  }
  if (tid == 0) rowptr[0] = 0;
}

__global__ void k_fill(const int* __restrict__ eidx, const int* __restrict__ rowptr,
                       int* __restrict__ cursor, int* __restrict__ csr_src){
  int e = blockIdx.x*blockDim.x + threadIdx.x;
  if (e >= ETOT) return;
  int dst, src;
  if (e < NEDGES){ src = eidx[e]; dst = eidx[NEDGES + e]; }
  else           { src = e - NEDGES; dst = src; }
  int pos = atomicAdd(&cursor[dst], 1);
  csr_src[rowptr[dst] + pos] = src;
}

// ---------------- x (fp32) -> bf16 row-major, K padded to KP0 ----------------
__global__ void k_xconv(const float* __restrict__ x, __hip_bfloat16* __restrict__ Ab){
  int idx = blockIdx.x*blockDim.x + threadIdx.x;
  if (idx >= NNODES*336) return;
  int r = idx / 336, k = idx % 336;
  Ab[(size_t)r * KP0 + k] = __float2bfloat16(x[idx]);
}

// ---------------- all 4 W -> bf16 B-fragment tiling, one launch ----------------
__global__ void k_wconv_all(const float* __restrict__ W0, const float* __restrict__ W1,
                            const float* __restrict__ W2, const float* __restrict__ W3,
                            __hip_bfloat16* __restrict__ Wt0, __hip_bfloat16* __restrict__ Wt1,
                            __hip_bfloat16* __restrict__ Wt2, __hip_bfloat16* __restrict__ Wt3){
  const int T0 = 16 * KP0 * 16;
  const int T1 = 16 * KP1 * 16;
  int idx = blockIdx.x*blockDim.x + threadIdx.x;
  const float* W; __hip_bfloat16* Wt; int K, Kp, li;
  if (idx < T0)              { W = W0; Wt = Wt0; K = 336; Kp = KP0; li = idx; }
  else if (idx < T0 +   T1)  { W = W1; Wt = Wt1; K = CH;  Kp = KP1; li = idx - T0; }
  else if (idx < T0 + 2*T1)  { W = W2; Wt = Wt2; K = CH;  Kp = KP1; li = idx - T0 - T1; }
  else if (idx < T0 + 3*T1)  { W = W3; Wt = Wt3; K = CH;  Kp = KP1; li = idx - T0 - 2*T1; }
  else return;
  int KC = Kp >> 5;
  int nt = li / (Kp * 16);
  int rem = li % (Kp * 16);
  int k = rem / 16;
  int n = rem % 16;
  int col = nt * 16 + n;
  float v = (k < K && col < CH) ? W[(size_t)k * CH + col] : 0.f;
  Wt[(((size_t)nt * KC + (k >> 5)) * 16 + n) * 32 + (k & 31)] = __float2bfloat16(v);
}

// ---------------- MFMA GEMM + fused attention scores ----------------
// h out: bf16 only (gather input). Scores e_src/e_dst computed from fp32 accumulators:
// per-lane predicated FMAs vs asrc/adst, 16-lane shuffle reduce, atomicAdd into
// esrc/edst (zeroed beforehand). 160K atomics/layer ~ 4us (k_pool scaling).
__global__ __launch_bounds__(256) void k_gemm_mfma(
    const __hip_bfloat16* __restrict__ A, const __hip_bfloat16* __restrict__ Wt,
    __hip_bfloat16* __restrict__ Cb, const float* __restrict__ asrc,
    const float* __restrict__ adst, float* __restrict__ esrc, float* __restrict__ edst,
    int M, int Kp){
  int wv = threadIdx.x >> 6, lane = threadIdx.x & 63;
  int n16 = lane & 15, q = lane >> 4;
  int KC = Kp >> 5;
  int rowbase = blockIdx.x * 64 + wv * 16;
  int bn = blockIdx.y * 64;
  int nt0 = bn >> 4;
  const __hip_bfloat16* ap = A  + (size_t)(rowbase + n16) * Kp + q * 8;
  const __hip_bfloat16* bp = Wt + ((size_t)nt0 * KC * 16 + n16) * 32 + q * 8;
  f32x4 ac0 = {0.f,0.f,0.f,0.f}, ac1 = ac0, ac2 = ac0, ac3 = ac0;
  for (int kc = 0; kc < KC; ++kc){
    bf16x8 a  = *(const bf16x8*)(ap + (size_t)kc * 32);
    bf16x8 b0 = *(const bf16x8*)(bp + ((size_t)0 * KC + kc) * 512);
    bf16x8 b1 = *(const bf16x8*)(bp + ((size_t)1 * KC + kc) * 512);
    bf16x8 b2 = *(const bf16x8*)(bp + ((size_t)2 * KC + kc) * 512);
    bf16x8 b3 = *(const bf16x8*)(bp + ((size_t)3 * KC + kc) * 512);
    ac0 = __builtin_amdgcn_mfma_f32_16x16x32_bf16(a, b0, ac0, 0, 0, 0);
    ac1 = __builtin_amdgcn_mfma_f32_16x16x32_bf16(a, b1, ac1, 0, 0, 0);
    ac2 = __builtin_amdgcn_mfma_f32_16x16x32_bf16(a, b2, ac2, 0, 0, 0);
    ac3 = __builtin_amdgcn_mfma_f32_16x16x32_bf16(a, b3, ac3, 0, 0, 0);
  }
  // fused scores: per-head partial dot of row with asrc/adst over this block's 64 cols
  float es0[4] = {}, es1[4] = {}, ed0a[4] = {}, ed1a[4] = {};
  #define SCORE_T(AC, T) { \
    int col = bn + (T)*16 + n16; \
    bool ok = col < CH; \
    float av = ok ? asrc[col] : 0.f; \
    float dv = ok ? adst[col] : 0.f; \
    bool hh = col >= HOUT; \
    float av0 = hh ? 0.f : av, av1 = hh ? av : 0.f; \
    float dv0 = hh ? 0.f : dv, dv1 = hh ? dv : 0.f; \
    _Pragma("unroll") \
    for (int r = 0; r < 4; ++r){ \
      es0[r] += AC[r]*av0; es1[r] += AC[r]*av1; \
      ed0a[r] += AC[r]*dv0; ed1a[r] += AC[r]*dv1; } }
  SCORE_T(ac0, 0) SCORE_T(ac1, 1) SCORE_T(ac2, 2) SCORE_T(ac3, 3)
  #undef SCORE_T
  #pragma unroll
  for (int off = 1; off < 16; off <<= 1){
    #pragma unroll
    for (int r = 0; r < 4; ++r){
      es0[r]  += __shfl_xor(es0[r],  off);
      es1[r]  += __shfl_xor(es1[r],  off);
      ed0a[r] += __shfl_xor(ed0a[r], off);
      ed1a[r] += __shfl_xor(ed1a[r], off);
    }
  }
  if (n16 == 0){
    #pragma unroll
    for (int r = 0; r < 4; ++r){
      int row = rowbase + q*4 + r;
      if (row < M){
        atomicAdd(&esrc[row*2+0], es0[r]);
        atomicAdd(&esrc[row*2+1], es1[r]);
        atomicAdd(&edst[row*2+0], ed0a[r]);
        atomicAdd(&edst[row*2+1], ed1a[r]);
      }
    }
  }
  // bf16 h store
  #pragma unroll
  for (int r = 0; r < 4; ++r){
    int row = rowbase + q * 4 + r;
    if (row >= M) continue;
    int col = bn + n16;
    __hip_bfloat16* cb = Cb + (size_t)row * CH + col;
    if (col      < CH) cb[0]  = __float2bfloat16(ac0[r]);
    if (col + 16 < CH) cb[16] = __float2bfloat16(ac1[r]);
    if (col + 32 < CH) cb[32] = __float2bfloat16(ac2[r]);
    if (col + 48 < CH) cb[48] = __float2bfloat16(ac3[r]);
  }
}

// ---------------- fused softmax + gather: block per node ----------------
// Phase A: e per edge -> LDS (+ local max); block-reduce max; exp + sum; block-reduce sum.
// Phase B: 4-wave column-split weighted gather over bf16 h. Epilogue: bias+relu, store
// bf16 to next layer's A (KP1 stride); zero the OTHER layer's esrc/edst buffers.
__global__ __launch_bounds__(256) void k_attn(const __hip_bfloat16* __restrict__ h,
                        const float* __restrict__ esrc, const float* __restrict__ edst,
                        const int* __restrict__ rowptr, const int* __restrict__ csr_src,
                        const float* __restrict__ bias, __hip_bfloat16* __restrict__ outb,
                        float* __restrict__ esZ, float* __restrict__ edZ){
  int node = blockIdx.x;
  int tid = threadIdx.x, wave = tid >> 6, lane = tid & 63;
  int start = rowptr[node], end = rowptr[node+1], deg = end - start;
  __shared__ int   s_src[DCAP];
  __shared__ float s_a0[DCAP], s_a1[DCAP];
  __shared__ float wred0[4], wred1[4];
  __shared__ float sh[4 * 256];
  float ed0 = edst[node*2+0], ed1 = edst[node*2+1];
  // phase A: raw scores -> LDS, local max
  float mx0 = -1e30f, mx1 = -1e30f;
  for (int i = tid; i < deg; i += 256){
    int src = csr_src[start + i];
    float e0 = esrc[src*2+0] + ed0; e0 = e0 > 0.f ? e0 : 0.2f*e0;
    float e1 = esrc[src*2+1] + ed1; e1 = e1 > 0.f ? e1 : 0.2f*e1;
    if (i < DCAP){ s_src[i] = src; s_a0[i] = e0; s_a1[i] = e1; }
    mx0 = fmaxf(mx0, e0); mx1 = fmaxf(mx1, e1);
  }
  for (int off = 32; off > 0; off >>= 1){
    mx0 = fmaxf(mx0, __shfl_xor(mx0, off));
    mx1 = fmaxf(mx1, __shfl_xor(mx1, off));
  }
  if (lane == 0){ wred0[wave] = mx0; wred1[wave] = mx1; }
  __syncthreads();
  mx0 = fmaxf(fmaxf(wred0[0], wred0[1]), fmaxf(wred0[2], wred0[3]));
  mx1 = fmaxf(fmaxf(wred1[0], wred1[1]), fmaxf(wred1[2], wred1[3]));
  __syncthreads();   // wred reuse below
  // phase A2: exp + sum (overwrite LDS with unnormalized alpha)
  float sm0 = 0.f, sm1 = 0.f;
  for (int i = tid; i < deg; i += 256){
    float e0, e1;
    if (i < DCAP){ e0 = s_a0[i]; e1 = s_a1[i]; }
    else {
      int src = csr_src[start + i];
      e0 = esrc[src*2+0] + ed0; e0 = e0 > 0.f ? e0 : 0.2f*e0;
      e1 = esrc[src*2+1] + ed1; e1 = e1 > 0.f ? e1 : 0.2f*e1;
    }
    float x0 = expf(e0 - mx0), x1 = expf(e1 - mx1);
    if (i < DCAP){ s_a0[i] = x0; s_a1[i] = x1; }
    sm0 += x0; sm1 += x1;
  }
  for (int off = 32; off > 0; off >>= 1){
    sm0 += __shfl_xor(sm0, off);
    sm1 += __shfl_xor(sm1, off);
  }
  if (lane == 0){ wred0[wave] = sm0; wred1[wave] = sm1; }
  __syncthreads();
  float inv0 = 1.f / ((wred0[0]+wred0[1]+wred0[2]+wred0[3]) + 1e-16f);
  float inv1 = 1.f / ((wred1[0]+wred1[1]+wred1[2]+wred1[3]) + 1e-16f);
  // phase B: gather (wave-split edges, lane-split columns), 2-unrolled
  bool c1h1 = (lane + 64) >= HOUT;
  bool c3ok = (lane + 192) < CH;
  float acc0=0.f, acc1=0.f, acc2=0.f, acc3=0.f;
  #define FETCH(I, S, A0, A1) { \
    if ((I) < DCAP){ S = s_src[I]; A0 = s_a0[I]*inv0; A1 = s_a1[I]*inv1; } \
    else { S = csr_src[start + (I)]; \
      float e0 = esrc[S*2+0] + ed0; e0 = e0 > 0.f ? e0 : 0.2f*e0; \
      float e1 = esrc[S*2+1] + ed1; e1 = e1 > 0.f ? e1 : 0.2f*e1; \
      A0 = expf(e0 - mx0)*inv0; A1 = expf(e1 - mx1)*inv1; } }
  int i = wave;
  for (; i + 4 < deg; i += 8){
    int sA, sB; float a0A,a1A,a0B,a1B;
    FETCH(i, sA, a0A, a1A)
    FETCH(i+4, sB, a0B, a1B)
    const __hip_bfloat16* hA = h + (size_t)sA * CH;
    const __hip_bfloat16* hB = h + (size_t)sB * CH;
    float wA = c1h1 ? a1A : a0A;
    float wB = c1h1 ? a1B : a0B;
    acc0 += a0A * __bfloat162float(hA[lane]);
    acc1 += wA  * __bfloat162float(hA[lane + 64]);
    acc2 += a1A * __bfloat162float(hA[lane + 128]);
    if (c3ok) acc3 += a1A * __bfloat162float(hA[lane + 192]);
    acc0 += a0B * __bfloat162float(hB[lane]);
    acc1 += wB  * __bfloat162float(hB[lane + 64]);
    acc2 += a1B * __bfloat162float(hB[lane + 128]);
    if (c3ok) acc3 += a1B * __bfloat162float(hB[lane + 192]);
  }
  if (i < deg){
    int sA; float a0A, a1A;
    FETCH(i, sA, a0A, a1A)
    const __hip_bfloat16* hA = h + (size_t)sA * CH;
    float wA = c1h1 ? a1A : a0A;
    acc0 += a0A * __bfloat162float(hA[lane]);
    acc1 += wA  * __bfloat162float(hA[lane + 64]);
    acc2 += a1A * __bfloat162float(hA[lane + 128]);
    if (c3ok) acc3 += a1A * __bfloat162float(hA[lane + 192]);
  }
  #undef FETCH
  float* shw = sh + wave * 256;
  shw[lane]        = acc0;
  shw[lane + 64]   = acc1;
  shw[lane + 128]  = acc2;
  if (c3ok) shw[lane + 192] = acc3;
  __syncthreads();
  if (tid < CH){
    float v = sh[tid] + sh[256 + tid] + sh[512 + tid] + sh[768 + tid] + bias[tid];
    v = v > 0.f ? v : 0.f;
    outb[(size_t)node * KP1 + tid] = __float2bfloat16(v);
  }
  if (tid < 2){     // prep next layer's score accumulators
    esZ[node*2 + tid] = 0.f;
    edZ[node*2 + tid] = 0.f;
  }
}

// ---------------- fused head: segmented mean pool (bf16 input) + 4-layer MLP -------------
__global__ __launch_bounds__(256) void k_head(const __hip_bfloat16* __restrict__ xb,
                        const int* __restrict__ gstart,
                        const float* __restrict__ lw1, const float* __restrict__ lb1,
                        const float* __restrict__ lw2, const float* __restrict__ lb2,
                        const float* __restrict__ lw3, const float* __restrict__ lb3,
                        const float* __restrict__ lw4, const float* __restrict__ lb4,
                        float* __restrict__ out){
  int g = blockIdx.x;
  int tid = threadIdx.x;
  int s = gstart[g], e = gstart[g+1];
  __shared__ float gvec[256];
  __shared__ float m1[200];
  __shared__ float m2[112];
  __shared__ float m3[112];
  if (tid < CH){
    float a0=0.f,a1=0.f,a2=0.f,a3=0.f;
    int n = s;
    for (; n + 3 < e; n += 4){
      a0 += __bfloat162float(xb[(size_t)n     * KP1 + tid]);
      a1 += __bfloat162float(xb[(size_t)(n+1) * KP1 + tid]);
      a2 += __bfloat162float(xb[(size_t)(n+2) * KP1 + tid]);
      a3 += __bfloat162float(xb[(size_t)(n+3) * KP1 + tid]);
    }
    for (; n < e; ++n) a0 += __bfloat162float(xb[(size_t)n * KP1 + tid]);
    float scale = 1.f / fmaxf((float)(e - s), 1.f);
    gvec[tid] = (a0 + a1 + a2 + a3) * scale;
  }
  __syncthreads();
  if (tid < 200){
    float a0=0.f,a1=0.f,a2=0.f,a3=0.f;
    int k = 0;
    for (; k + 3 < CH; k += 4){
      a0 += gvec[k]   * lw1[(size_t)k     * 200 + tid];
      a1 += gvec[k+1] * lw1[(size_t)(k+1) * 200 + tid];
      a2 += gvec[k+2] * lw1[(size_t)(k+2) * 200 + tid];
      a3 += gvec[k+3] * lw1[(size_t)(k+3) * 200 + tid];
    }
    for (; k < CH; ++k) a0 += gvec[k] * lw1[(size_t)k * 200 + tid];
    float v = a0 + a1 + a2 + a3 + lb1[tid];
    m1[tid] = v > 0.f ? v : 0.f;
  }
  __syncthreads();
  if (tid < 100){
    float a0=0.f,a1=0.f,a2=0.f,a3=0.f;
    for (int k = 0; k + 3 < 200; k += 4){
      a0 += m1[k]   * lw2[(size_t)k     * 100 + tid];
      a1 += m1[k+1] * lw2[(size_t)(k+1) * 100 + tid];
      a2 += m1[k+2] * lw2[(size_t)(k+2) * 100 + tid];
      a3 += m1[k+3] * lw2[(size_t)(k+3) * 100 + tid];
    }
    float v = a0 + a1 + a2 + a3 + lb2[tid];
    m2[tid] = v > 0.f ? v : 0.f;
  }
  __syncthreads();
  if (tid < 100){
    float a0=0.f,a1=0.f,a2=0.f,a3=0.f;
    for (int k = 0; k + 3 < 100; k += 4){
      a0 += m2[k]   * lw3[(size_t)k     * 100 + tid];
      a1 += m2[k+1] * lw3[(size_t)(k+1) * 100 + tid];
      a2 += m2[k+2] * lw3[(size_t)(k+2) * 100 + tid];
      a3 += m2[k+3] * lw3[(size_t)(k+3) * 100 + tid];
    }
    float v = a0 + a1 + a2 + a3 + lb3[tid];
    m3[tid] = v > 0.f ? v : 0.f;
  }
  __syncthreads();
  if (tid < 29){
    float a0=0.f,a1=0.f,a2=0.f,a3=0.f;
    for (int k = 0; k + 3 < 100; k += 4){
      a0 += m3[k]   * lw4[(size_t)k     * 29 + tid];
      a1 += m3[k+1] * lw4[(size_t)(k+1) * 29 + tid];
      a2 += m3[k+2] * lw4[(size_t)(k+2) * 29 + tid];
      a3 += m3[k+3] * lw4[(size_t)(k+3) * 29 + tid];
    }
    out[(size_t)g * 29 + tid] = a0 + a1 + a2 + a3 + lb4[tid];
  }
}

// ---------------- launch ----------------
extern "C" void kernel_launch(void* const* d_in, const int* in_sizes, int n_in,
                              void* d_out, int out_size, void* d_ws, size_t ws_size,
                              hipStream_t stream){
  const float* x   = (const float*)d_in[0];
  const int* eidx  = (const int*)d_in[1];
  const int* batch = (const int*)d_in[2];

  char* ws = (char*)d_ws;
  size_t off = 0;
  auto alloc = [&](size_t bytes)->void*{
    void* p = ws + off;
    off = (off + bytes + 255) & ~(size_t)255;
    return p;
  };
  __hip_bfloat16* hb16 = (__hip_bfloat16*)alloc((size_t)NNODES * CH * 2);
  __hip_bfloat16* Abf0 = (__hip_bfloat16*)alloc((size_t)MPAD * KP0 * 2);
  __hip_bfloat16* Abf  = (__hip_bfloat16*)alloc((size_t)MPAD * KP1 * 2);
  __hip_bfloat16* Wt0  = (__hip_bfloat16*)alloc((size_t)16 * KP0 * 16 * 2);
  __hip_bfloat16* Wt1  = (__hip_bfloat16*)alloc((size_t)16 * KP1 * 16 * 2);
  __hip_bfloat16* Wt2  = (__hip_bfloat16*)alloc((size_t)16 * KP1 * 16 * 2);
  __hip_bfloat16* Wt3  = (__hip_bfloat16*)alloc((size_t)16 * KP1 * 16 * 2);
  // ---- zero-initialized region (single memset): deg, cursor, esA, edA, esB, edB ----
  size_t zbeg = off;
  int*   deg  = (int*)  alloc((size_t)NNODES * 4);
  int*   cursor = (int*)alloc((size_t)NNODES * 4);
  float* esA  = (float*)alloc((size_t)NNODES * 2 * 4);
  float* edA  = (float*)alloc((size_t)NNODES * 2 * 4);
  float* esB  = (float*)alloc((size_t)NNODES * 2 * 4);
  float* edB  = (float*)alloc((size_t)NNODES * 2 * 4);
  size_t zend = off;
  int*    rowptr  = (int*)   alloc((size_t)(NNODES + 1) * 4);
  int*    csr_src = (int*)   alloc((size_t)ETOT * 4);
  int*    gstart  = (int*)   alloc((size_t)(NGRAPH + 1) * 4);

  hipMemsetAsync(ws + zbeg, 0, zend - zbeg, stream);

  k_deg <<<(ETOT + 255)/256, 256, 0, stream>>>(eidx, deg, batch, gstart);
  k_scan<<<1, 1024, 0, stream>>>(deg, rowptr);
  k_fill<<<(ETOT + 255)/256, 256, 0, stream>>>(eidx, rowptr, cursor, csr_src);

  k_xconv<<<(NNODES*336 + 255)/256, 256, 0, stream>>>(x, Abf0);
  {
    int wtot = 16*KP0*16 + 3*16*KP1*16;
    k_wconv_all<<<(wtot + 255)/256, 256, 0, stream>>>(
        (const float*)d_in[3], (const float*)d_in[7], (const float*)d_in[11], (const float*)d_in[15],
        Wt0, Wt1, Wt2, Wt3);
  }

  const __hip_bfloat16* Wts[4] = {Wt0, Wt1, Wt2, Wt3};
  for (int L = 0; L < 4; ++L){
    const float* as_ = (const float*)d_in[4 + 4*L];
    const float* ad_ = (const float*)d_in[5 + 4*L];
    const float* bb  = (const float*)d_in[6 + 4*L];
    int Kp = (L == 0) ? KP0 : KP1;
    const __hip_bfloat16* Ain = (L == 0) ? Abf0 : Abf;
    float* es = (L & 1) ? esB : esA;   // this layer's accumulators (pre-zeroed)
    float* ed = (L & 1) ? edB : edA;
    float* esZ = (L & 1) ? esA : esB;  // zeroed by k_attn for next layer
    float* edZ = (L & 1) ? edA : edB;

    dim3 gg(MPAD/64, 4);
    k_gemm_mfma<<<gg, 256, 0, stream>>>(Ain, Wts[L], hb16, as_, ad_, es, ed, NNODES, Kp);
    k_attn<<<NNODES, 256, 0, stream>>>(hb16, es, ed, rowptr, csr_src, bb, Abf, esZ, edZ);
  }

  const float* lw1 = (const float*)d_in[19];
  const float* lb1 = (const float*)d_in[20];
  const float* lw2 = (const float*)d_in[21];
  const float* lb2 = (const float*)d_in[22];
  const float* lw3 = (const float*)d_in[23];
  const float* lb3 = (const float*)d_in[24];
  const float* lw4 = (const float*)d_in[25];
  const float* lb4 = (const float*)d_in[26];

  k_head<<<NGRAPH, 256, 0, stream>>>(Abf, gstart, lw1, lb1, lw2, lb2, lw3, lb3,
                                     lw4, lb4, (float*)d_out);
}

// Round 10
// 365.359 us; speedup vs baseline: 2.6086x; 1.1191x over previous
//
#include <hip/hip_runtime.h>
#include <hip/hip_bf16.h>

#define NNODES 10000
#define NEDGES 320000
#define ETOT   (NEDGES + NNODES)
#define NGRAPH 100
#define CH     250   // HEADS*OUT
#define HOUT   125
#define MPAD   10048 // 157 * 64
#define KP0    352   // layer-0 K=336 padded to 32-multiple
#define KP1    256   // layers 1-3 K=250 padded
#define HPAD   256   // hb16 row stride (bf16) -> 512B rows, 8B-aligned lane chunks
#define DCAP   256   // per-node edge cache in LDS

typedef __attribute__((ext_vector_type(8))) short bf16x8;
typedef __attribute__((ext_vector_type(4))) float f32x4;

static __device__ __forceinline__ float bfbits2f(unsigned int u){
  union{ unsigned int i; float f; } v; v.i = u << 16; return v.f;
}
static __device__ __forceinline__ unsigned short f2bfbits(float f){
  __hip_bfloat16 b = __float2bfloat16(f);
  union{ __hip_bfloat16 b; unsigned short s; } v; v.b = b; return v.s;
}

// ---------------- deg count + graph boundaries (fused) ----------------
__global__ void k_deg(const int* __restrict__ eidx, int* __restrict__ deg,
                      const int* __restrict__ batch, int* __restrict__ gstart){
  int e = blockIdx.x*blockDim.x + threadIdx.x;
  if (e < ETOT){
    int dst = (e < NEDGES) ? eidx[NEDGES + e] : (e - NEDGES);
    atomicAdd(&deg[dst], 1);
  }
  if (e < NNODES){
    int b1 = batch[e];
    int b0 = (e == 0) ? -1 : batch[e-1];
    for (int b = b0 + 1; b <= b1; ++b) gstart[b] = e;
    if (e == NNODES - 1){
      for (int b = b1 + 1; b <= NGRAPH; ++b) gstart[b] = NNODES;
    }
  }
}

// ---------------- exclusive scan of deg -> rowptr (1 block, 1024 thr) ----------
__global__ __launch_bounds__(1024) void k_scan(const int* __restrict__ deg, int* __restrict__ rowptr){
  const int CHUNK = 10;
  int tid = threadIdx.x;
  int base = tid * CHUNK;
  int sum = 0;
  #pragma unroll
  for (int u = 0; u < CHUNK; ++u){
    int i = base + u;
    sum += (i < NNODES) ? deg[i] : 0;
  }
  int lane = tid & 63, wv = tid >> 6;
  int v = sum;
  #pragma unroll
  for (int off = 1; off < 64; off <<= 1){
    int t = __shfl_up(v, off);
    if (lane >= off) v += t;
  }
  __shared__ int wtot[16];
  __shared__ int woff[16];
  if (lane == 63) wtot[wv] = v;
  __syncthreads();
  if (tid == 0){
    int acc = 0;
    #pragma unroll
    for (int w = 0; w < 16; ++w){ woff[w] = acc; acc += wtot[w]; }
  }
  __syncthreads();
  int run = woff[wv] + v - sum;
  #pragma unroll
  for (int u = 0; u < CHUNK; ++u){
    int i = base + u;
    if (i < NNODES){
      run += deg[i];
      rowptr[i+1] = run;
    }
  }
  if (tid == 0) rowptr[0] = 0;
}

__global__ void k_fill(const int* __restrict__ eidx, const int* __restrict__ rowptr,
                       int* __restrict__ cursor, int* __restrict__ csr_src){
  int e = blockIdx.x*blockDim.x + threadIdx.x;
  if (e >= ETOT) return;
  int dst, src;
  if (e < NEDGES){ src = eidx[e]; dst = eidx[NEDGES + e]; }
  else           { src = e - NEDGES; dst = src; }
  int pos = atomicAdd(&cursor[dst], 1);
  csr_src[rowptr[dst] + pos] = src;
}

// ---------------- x (fp32) -> bf16 row-major, K padded to KP0 ----------------
__global__ void k_xconv(const float* __restrict__ x, __hip_bfloat16* __restrict__ Ab){
  int idx = blockIdx.x*blockDim.x + threadIdx.x;
  if (idx >= NNODES*336) return;
  int r = idx / 336, k = idx % 336;
  Ab[(size_t)r * KP0 + k] = __float2bfloat16(x[idx]);
}

// ---------------- all 4 W -> bf16 B-fragment tiling, one launch ----------------
__global__ void k_wconv_all(const float* __restrict__ W0, const float* __restrict__ W1,
                            const float* __restrict__ W2, const float* __restrict__ W3,
                            __hip_bfloat16* __restrict__ Wt0, __hip_bfloat16* __restrict__ Wt1,
                            __hip_bfloat16* __restrict__ Wt2, __hip_bfloat16* __restrict__ Wt3){
  const int T0 = 16 * KP0 * 16;
  const int T1 = 16 * KP1 * 16;
  int idx = blockIdx.x*blockDim.x + threadIdx.x;
  const float* W; __hip_bfloat16* Wt; int K, Kp, li;
  if (idx < T0)              { W = W0; Wt = Wt0; K = 336; Kp = KP0; li = idx; }
  else if (idx < T0 +   T1)  { W = W1; Wt = Wt1; K = CH;  Kp = KP1; li = idx - T0; }
  else if (idx < T0 + 2*T1)  { W = W2; Wt = Wt2; K = CH;  Kp = KP1; li = idx - T0 - T1; }
  else if (idx < T0 + 3*T1)  { W = W3; Wt = Wt3; K = CH;  Kp = KP1; li = idx - T0 - 2*T1; }
  else return;
  int KC = Kp >> 5;
  int nt = li / (Kp * 16);
  int rem = li % (Kp * 16);
  int k = rem / 16;
  int n = rem % 16;
  int col = nt * 16 + n;
  float v = (k < K && col < CH) ? W[(size_t)k * CH + col] : 0.f;
  Wt[(((size_t)nt * KC + (k >> 5)) * 16 + n) * 32 + (k & 31)] = __float2bfloat16(v);
}

// ---------------- MFMA GEMM + fused attention scores ----------------
__global__ __launch_bounds__(256) void k_gemm_mfma(
    const __hip_bfloat16* __restrict__ A, const __hip_bfloat16* __restrict__ Wt,
    __hip_bfloat16* __restrict__ Cb, const float* __restrict__ asrc,
    const float* __restrict__ adst, float* __restrict__ esrc, float* __restrict__ edst,
    int M, int Kp){
  int wv = threadIdx.x >> 6, lane = threadIdx.x & 63;
  int n16 = lane & 15, q = lane >> 4;
  int KC = Kp >> 5;
  int rowbase = blockIdx.x * 64 + wv * 16;
  int bn = blockIdx.y * 64;
  int nt0 = bn >> 4;
  const __hip_bfloat16* ap = A  + (size_t)(rowbase + n16) * Kp + q * 8;
  const __hip_bfloat16* bp = Wt + ((size_t)nt0 * KC * 16 + n16) * 32 + q * 8;
  f32x4 ac0 = {0.f,0.f,0.f,0.f}, ac1 = ac0, ac2 = ac0, ac3 = ac0;
  for (int kc = 0; kc < KC; ++kc){
    bf16x8 a  = *(const bf16x8*)(ap + (size_t)kc * 32);
    bf16x8 b0 = *(const bf16x8*)(bp + ((size_t)0 * KC + kc) * 512);
    bf16x8 b1 = *(const bf16x8*)(bp + ((size_t)1 * KC + kc) * 512);
    bf16x8 b2 = *(const bf16x8*)(bp + ((size_t)2 * KC + kc) * 512);
    bf16x8 b3 = *(const bf16x8*)(bp + ((size_t)3 * KC + kc) * 512);
    ac0 = __builtin_amdgcn_mfma_f32_16x16x32_bf16(a, b0, ac0, 0, 0, 0);
    ac1 = __builtin_amdgcn_mfma_f32_16x16x32_bf16(a, b1, ac1, 0, 0, 0);
    ac2 = __builtin_amdgcn_mfma_f32_16x16x32_bf16(a, b2, ac2, 0, 0, 0);
    ac3 = __builtin_amdgcn_mfma_f32_16x16x32_bf16(a, b3, ac3, 0, 0, 0);
  }
  float es0[4] = {}, es1[4] = {}, ed0a[4] = {}, ed1a[4] = {};
  #define SCORE_T(AC, T) { \
    int col = bn + (T)*16 + n16; \
    bool ok = col < CH; \
    float av = ok ? asrc[col] : 0.f; \
    float dv = ok ? adst[col] : 0.f; \
    bool hh = col >= HOUT; \
    float av0 = hh ? 0.f : av, av1 = hh ? av : 0.f; \
    float dv0 = hh ? 0.f : dv, dv1 = hh ? dv : 0.f; \
    _Pragma("unroll") \
    for (int r = 0; r < 4; ++r){ \
      es0[r] += AC[r]*av0; es1[r] += AC[r]*av1; \
      ed0a[r] += AC[r]*dv0; ed1a[r] += AC[r]*dv1; } }
  SCORE_T(ac0, 0) SCORE_T(ac1, 1) SCORE_T(ac2, 2) SCORE_T(ac3, 3)
  #undef SCORE_T
  #pragma unroll
  for (int off = 1; off < 16; off <<= 1){
    #pragma unroll
    for (int r = 0; r < 4; ++r){
      es0[r]  += __shfl_xor(es0[r],  off);
      es1[r]  += __shfl_xor(es1[r],  off);
      ed0a[r] += __shfl_xor(ed0a[r], off);
      ed1a[r] += __shfl_xor(ed1a[r], off);
    }
  }
  if (n16 == 0){
    #pragma unroll
    for (int r = 0; r < 4; ++r){
      int row = rowbase + q*4 + r;
      if (row < M){
        atomicAdd(&esrc[row*2+0], es0[r]);
        atomicAdd(&esrc[row*2+1], es1[r]);
        atomicAdd(&edst[row*2+0], ed0a[r]);
        atomicAdd(&edst[row*2+1], ed1a[r]);
      }
    }
  }
  #pragma unroll
  for (int r = 0; r < 4; ++r){
    int row = rowbase + q * 4 + r;
    if (row >= M) continue;
    int col = bn + n16;
    __hip_bfloat16* cb = Cb + (size_t)row * HPAD + col;
    if (col      < CH) cb[0]  = __float2bfloat16(ac0[r]);
    if (col + 16 < CH) cb[16] = __float2bfloat16(ac1[r]);
    if (col + 32 < CH) cb[32] = __float2bfloat16(ac2[r]);
    if (col + 48 < CH) cb[48] = __float2bfloat16(ac3[r]);
  }
}

// ---------------- fused softmax + gather: block per node, 8B vector gather ----------------
// Softmax without max-subtraction (shift-invariant; scores O(5), exp safe in fp32).
// Phase A (single pass): e -> exp -> LDS + sum reduce. Phase B: wave-split edges,
// lane L gathers cols [4L,4L+4) as one uint2. h rows padded to HPAD (finite poison pad).
__global__ __launch_bounds__(256) void k_attn(const __hip_bfloat16* __restrict__ h,
                        const float* __restrict__ esrc, const float* __restrict__ edst,
                        const int* __restrict__ rowptr, const int* __restrict__ csr_src,
                        const float* __restrict__ bias, __hip_bfloat16* __restrict__ outb,
                        float* __restrict__ esZ, float* __restrict__ edZ){
  int node = blockIdx.x;
  int tid = threadIdx.x, wave = tid >> 6, lane = tid & 63;
  int start = rowptr[node], deg = rowptr[node+1] - start;
  __shared__ int   s_src[DCAP];
  __shared__ float s_x0[DCAP], s_x1[DCAP];
  __shared__ float wred0[4], wred1[4];
  __shared__ float sh[4 * 256];
  float ed0 = edst[node*2+0], ed1 = edst[node*2+1];
  // phase A: exp(leaky(e)) -> LDS, block sum
  float sm0 = 0.f, sm1 = 0.f;
  for (int i = tid; i < deg; i += 256){
    int src = csr_src[start + i];
    float e0 = esrc[src*2+0] + ed0; e0 = e0 > 0.f ? e0 : 0.2f*e0;
    float e1 = esrc[src*2+1] + ed1; e1 = e1 > 0.f ? e1 : 0.2f*e1;
    float x0 = __expf(e0), x1 = __expf(e1);
    if (i < DCAP){ s_src[i] = src; s_x0[i] = x0; s_x1[i] = x1; }
    sm0 += x0; sm1 += x1;
  }
  for (int off = 32; off > 0; off >>= 1){
    sm0 += __shfl_xor(sm0, off);
    sm1 += __shfl_xor(sm1, off);
  }
  if (lane == 0){ wred0[wave] = sm0; wred1[wave] = sm1; }
  __syncthreads();
  float inv0 = 1.f / ((wred0[0]+wred0[1]+wred0[2]+wred0[3]) + 1e-16f);
  float inv1 = 1.f / ((wred1[0]+wred1[1]+wred1[2]+wred1[3]) + 1e-16f);
  // phase B: per-lane 4 consecutive cols, one 8B load per edge
  int c0 = 4*lane;
  bool h0_0 = (c0    ) < HOUT, h0_1 = (c0 + 1) < HOUT;
  bool h0_2 = (c0 + 2) < HOUT, h0_3 = (c0 + 3) < HOUT;
  float acc0=0.f, acc1=0.f, acc2=0.f, acc3=0.f;
  #define FETCH(I, S, A0, A1) { \
    if ((I) < DCAP){ S = s_src[I]; A0 = s_x0[I]*inv0; A1 = s_x1[I]*inv1; } \
    else { S = csr_src[start + (I)]; \
      float e0 = esrc[S*2+0] + ed0; e0 = e0 > 0.f ? e0 : 0.2f*e0; \
      float e1 = esrc[S*2+1] + ed1; e1 = e1 > 0.f ? e1 : 0.2f*e1; \
      A0 = __expf(e0)*inv0; A1 = __expf(e1)*inv1; } }
  #define GATHER(S, A0, A1) { \
    uint2 d = *(const uint2*)(h + (size_t)(S) * HPAD + c0); \
    acc0 += (h0_0 ? A0 : A1) * bfbits2f(d.x & 0xffffu); \
    acc1 += (h0_1 ? A0 : A1) * bfbits2f(d.x >> 16); \
    acc2 += (h0_2 ? A0 : A1) * bfbits2f(d.y & 0xffffu); \
    acc3 += (h0_3 ? A0 : A1) * bfbits2f(d.y >> 16); }
  int i = wave;
  for (; i + 4 < deg; i += 8){
    int sA, sB; float a0A,a1A,a0B,a1B;
    FETCH(i, sA, a0A, a1A)
    FETCH(i+4, sB, a0B, a1B)
    GATHER(sA, a0A, a1A)
    GATHER(sB, a0B, a1B)
  }
  if (i < deg){
    int sA; float a0A, a1A;
    FETCH(i, sA, a0A, a1A)
    GATHER(sA, a0A, a1A)
  }
  #undef GATHER
  #undef FETCH
  float* shw = sh + wave * 256;
  *(float4*)&shw[c0] = make_float4(acc0, acc1, acc2, acc3);
  __syncthreads();
  if (tid < 62){   // cols 4t..4t+3, all < 250 for t<62; t=62 tail below
    int c = 4*tid;
    float4 b4 = *(const float4*)&bias[c];
    float v0 = sh[c]   + sh[256+c]   + sh[512+c]   + sh[768+c]   + b4.x;
    float v1 = sh[c+1] + sh[256+c+1] + sh[512+c+1] + sh[768+c+1] + b4.y;
    float v2 = sh[c+2] + sh[256+c+2] + sh[512+c+2] + sh[768+c+2] + b4.z;
    float v3 = sh[c+3] + sh[256+c+3] + sh[512+c+3] + sh[768+c+3] + b4.w;
    v0 = v0 > 0.f ? v0 : 0.f; v1 = v1 > 0.f ? v1 : 0.f;
    v2 = v2 > 0.f ? v2 : 0.f; v3 = v3 > 0.f ? v3 : 0.f;
    ushort4 o; o.x = f2bfbits(v0); o.y = f2bfbits(v1); o.z = f2bfbits(v2); o.w = f2bfbits(v3);
    *(ushort4*)(outb + (size_t)node * KP1 + c) = o;
  } else if (tid == 62){  // cols 248, 249
    #pragma unroll
    for (int j = 0; j < 2; ++j){
      int c = 248 + j;
      float v = sh[c] + sh[256+c] + sh[512+c] + sh[768+c] + bias[c];
      v = v > 0.f ? v : 0.f;
      outb[(size_t)node * KP1 + c] = __float2bfloat16(v);
    }
  }
  if (tid < 2){
    esZ[node*2 + tid] = 0.f;
    edZ[node*2 + tid] = 0.f;
  }
}

// ---------------- fused head: segmented mean pool (bf16 input) + 4-layer MLP -------------
__global__ __launch_bounds__(256) void k_head(const __hip_bfloat16* __restrict__ xb,
                        const int* __restrict__ gstart,
                        const float* __restrict__ lw1, const float* __restrict__ lb1,
                        const float* __restrict__ lw2, const float* __restrict__ lb2,
                        const float* __restrict__ lw3, const float* __restrict__ lb3,
                        const float* __restrict__ lw4, const float* __restrict__ lb4,
                        float* __restrict__ out){
  int g = blockIdx.x;
  int tid = threadIdx.x;
  int s = gstart[g], e = gstart[g+1];
  __shared__ float gvec[256];
  __shared__ float m1[200];
  __shared__ float m2[112];
  __shared__ float m3[112];
  if (tid < CH){
    float a0=0.f,a1=0.f,a2=0.f,a3=0.f;
    int n = s;
    for (; n + 3 < e; n += 4){
      a0 += __bfloat162float(xb[(size_t)n     * KP1 + tid]);
      a1 += __bfloat162float(xb[(size_t)(n+1) * KP1 + tid]);
      a2 += __bfloat162float(xb[(size_t)(n+2) * KP1 + tid]);
      a3 += __bfloat162float(xb[(size_t)(n+3) * KP1 + tid]);
    }
    for (; n < e; ++n) a0 += __bfloat162float(xb[(size_t)n * KP1 + tid]);
    float scale = 1.f / fmaxf((float)(e - s), 1.f);
    gvec[tid] = (a0 + a1 + a2 + a3) * scale;
  }
  __syncthreads();
  if (tid < 200){
    float a0=0.f,a1=0.f,a2=0.f,a3=0.f;
    int k = 0;
    for (; k + 3 < CH; k += 4){
      a0 += gvec[k]   * lw1[(size_t)k     * 200 + tid];
      a1 += gvec[k+1] * lw1[(size_t)(k+1) * 200 + tid];
      a2 += gvec[k+2] * lw1[(size_t)(k+2) * 200 + tid];
      a3 += gvec[k+3] * lw1[(size_t)(k+3) * 200 + tid];
    }
    for (; k < CH; ++k) a0 += gvec[k] * lw1[(size_t)k * 200 + tid];
    float v = a0 + a1 + a2 + a3 + lb1[tid];
    m1[tid] = v > 0.f ? v : 0.f;
  }
  __syncthreads();
  if (tid < 100){
    float a0=0.f,a1=0.f,a2=0.f,a3=0.f;
    for (int k = 0; k + 3 < 200; k += 4){
      a0 += m1[k]   * lw2[(size_t)k     * 100 + tid];
      a1 += m1[k+1] * lw2[(size_t)(k+1) * 100 + tid];
      a2 += m1[k+2] * lw2[(size_t)(k+2) * 100 + tid];
      a3 += m1[k+3] * lw2[(size_t)(k+3) * 100 + tid];
    }
    float v = a0 + a1 + a2 + a3 + lb2[tid];
    m2[tid] = v > 0.f ? v : 0.f;
  }
  __syncthreads();
  if (tid < 100){
    float a0=0.f,a1=0.f,a2=0.f,a3=0.f;
    for (int k = 0; k + 3 < 100; k += 4){
      a0 += m2[k]   * lw3[(size_t)k     * 100 + tid];
      a1 += m2[k+1] * lw3[(size_t)(k+1) * 100 + tid];
      a2 += m2[k+2] * lw3[(size_t)(k+2) * 100 + tid];
      a3 += m2[k+3] * lw3[(size_t)(k+3) * 100 + tid];
    }
    float v = a0 + a1 + a2 + a3 + lb3[tid];
    m3[tid] = v > 0.f ? v : 0.f;
  }
  __syncthreads();
  if (tid < 29){
    float a0=0.f,a1=0.f,a2=0.f,a3=0.f;
    for (int k = 0; k + 3 < 100; k += 4){
      a0 += m3[k]   * lw4[(size_t)k     * 29 + tid];
      a1 += m3[k+1] * lw4[(size_t)(k+1) * 29 + tid];
      a2 += m3[k+2] * lw4[(size_t)(k+2) * 29 + tid];
      a3 += m3[k+3] * lw4[(size_t)(k+3) * 29 + tid];
    }
    out[(size_t)g * 29 + tid] = a0 + a1 + a2 + a3 + lb4[tid];
  }
}

// ---------------- launch ----------------
extern "C" void kernel_launch(void* const* d_in, const int* in_sizes, int n_in,
                              void* d_out, int out_size, void* d_ws, size_t ws_size,
                              hipStream_t stream){
  const float* x   = (const float*)d_in[0];
  const int* eidx  = (const int*)d_in[1];
  const int* batch = (const int*)d_in[2];

  char* ws = (char*)d_ws;
  size_t off = 0;
  auto alloc = [&](size_t bytes)->void*{
    void* p = ws + off;
    off = (off + bytes + 255) & ~(size_t)255;
    return p;
  };
  __hip_bfloat16* hb16 = (__hip_bfloat16*)alloc((size_t)NNODES * HPAD * 2);
  __hip_bfloat16* Abf0 = (__hip_bfloat16*)alloc((size_t)MPAD * KP0 * 2);
  __hip_bfloat16* Abf  = (__hip_bfloat16*)alloc((size_t)MPAD * KP1 * 2);
  __hip_bfloat16* Wt0  = (__hip_bfloat16*)alloc((size_t)16 * KP0 * 16 * 2);
  __hip_bfloat16* Wt1  = (__hip_bfloat16*)alloc((size_t)16 * KP1 * 16 * 2);
  __hip_bfloat16* Wt2  = (__hip_bfloat16*)alloc((size_t)16 * KP1 * 16 * 2);
  __hip_bfloat16* Wt3  = (__hip_bfloat16*)alloc((size_t)16 * KP1 * 16 * 2);
  size_t zbeg = off;
  int*   deg    = (int*)  alloc((size_t)NNODES * 4);
  int*   cursor = (int*)  alloc((size_t)NNODES * 4);
  float* esA  = (float*)alloc((size_t)NNODES * 2 * 4);
  float* edA  = (float*)alloc((size_t)NNODES * 2 * 4);
  float* esB  = (float*)alloc((size_t)NNODES * 2 * 4);
  float* edB  = (float*)alloc((size_t)NNODES * 2 * 4);
  size_t zend = off;
  int*    rowptr  = (int*)   alloc((size_t)(NNODES + 1) * 4);
  int*    csr_src = (int*)   alloc((size_t)ETOT * 4);
  int*    gstart  = (int*)   alloc((size_t)(NGRAPH + 1) * 4);

  hipMemsetAsync(ws + zbeg, 0, zend - zbeg, stream);

  k_deg <<<(ETOT + 255)/256, 256, 0, stream>>>(eidx, deg, batch, gstart);
  k_scan<<<1, 1024, 0, stream>>>(deg, rowptr);
  k_fill<<<(ETOT + 255)/256, 256, 0, stream>>>(eidx, rowptr, cursor, csr_src);

  k_xconv<<<(NNODES*336 + 255)/256, 256, 0, stream>>>(x, Abf0);
  {
    int wtot = 16*KP0*16 + 3*16*KP1*16;
    k_wconv_all<<<(wtot + 255)/256, 256, 0, stream>>>(
        (const float*)d_in[3], (const float*)d_in[7], (const float*)d_in[11], (const float*)d_in[15],
        Wt0, Wt1, Wt2, Wt3);
  }

  const __hip_bfloat16* Wts[4] = {Wt0, Wt1, Wt2, Wt3};
  for (int L = 0; L < 4; ++L){
    const float* as_ = (const float*)d_in[4 + 4*L];
    const float* ad_ = (const float*)d_in[5 + 4*L];
    const float* bb  = (const float*)d_in[6 + 4*L];
    int Kp = (L == 0) ? KP0 : KP1;
    const __hip_bfloat16* Ain = (L == 0) ? Abf0 : Abf;
    float* es  = (L & 1) ? esB : esA;
    float* ed  = (L & 1) ? edB : edA;
    float* esZ = (L & 1) ? esA : esB;
    float* edZ = (L & 1) ? edA : edB;

    dim3 gg(MPAD/64, 4);
    k_gemm_mfma<<<gg, 256, 0, stream>>>(Ain, Wts[L], hb16, as_, ad_, es, ed, NNODES, Kp);
    k_attn<<<NNODES, 256, 0, stream>>>(hb16, es, ed, rowptr, csr_src, bb, Abf, esZ, edZ);
  }

  const float* lw1 = (const float*)d_in[19];
  const float* lb1 = (const float*)d_in[20];
  const float* lw2 = (const float*)d_in[21];
  const float* lb2 = (const float*)d_in[22];
  const float* lw3 = (const float*)d_in[23];
  const float* lb3 = (const float*)d_in[24];
  const float* lw4 = (const float*)d_in[25];
  const float* lb4 = (const float*)d_in[26];

  k_head<<<NGRAPH, 256, 0, stream>>>(Abf, gstart, lw1, lb1, lw2, lb2, lw3, lb3,
                                     lw4, lb4, (float*)d_out);
}